// Round 6
// baseline (276.367 us; speedup 1.0000x reference)
//
#include <hip/hip_runtime.h>

// x:(1,64,64,768) -> n=4096 tokens, DIM=768, 12 heads x 64 dim
#define NTOK 4096
#define DIMD 768
#define NHD  12
#define HDD  64
#define DK   800   // extended K: 768 x | 4 lora-q | 4 lora-v | 24 zero

typedef float  f32x4  __attribute__((ext_vector_type(4)));
typedef float  f32x16 __attribute__((ext_vector_type(16)));
typedef short  s16x8  __attribute__((ext_vector_type(8)));

#define MFMA16(a, b, c) __builtin_amdgcn_mfma_f32_16x16x32_bf16(a, b, c, 0, 0, 0)
#define MFMA32(a, b, c) __builtin_amdgcn_mfma_f32_32x32x16_bf16(a, b, c, 0, 0, 0)

__device__ inline short f2b(float f) {  // fp32 -> bf16 RNE
  unsigned u = __float_as_uint(f);
  u += 0x7FFFu + ((u >> 16) & 1u);
  return (short)(u >> 16);
}
__device__ inline float b2f(short s) {
  return __uint_as_float(((unsigned)(unsigned short)s) << 16);
}
__device__ inline void gl_lds16(const short* g, short* l) {
  __builtin_amdgcn_global_load_lds(
      (const __attribute__((address_space(1))) unsigned int*)g,
      (__attribute__((address_space(3))) unsigned int*)l, 16, 0, 0);
}

// ws layout (float units):
//   xe    @0         bf16 [4096][800]  (1,638,400 f)
//   we    @1638400   bf16 [2304][800]  (921,600 f)
//   wpb   @2560000   bf16 [768][768]   (294,912 f)
//   qkvb  @2854912   bf16 [3][12][4096][64] (4,718,592 f)
//   vtb   @7573504   bf16 [12][64][4096]    (1,572,864 f)
//   attnb @9146368   bf16 [4096][768]       (1,572,864 f)
// total 10,719,232 floats = 42.9 MB

// ---------------------------------------------------------------------------
// Kernel A: build extended weights we[2304][800] and wpb[768][768] (bf16)
__global__ __launch_bounds__(64)
void k_prep_w(const float* __restrict__ Wqkv, const float* __restrict__ Bq,
              const float* __restrict__ Bv, const float* __restrict__ Wp,
              short* __restrict__ we, short* __restrict__ wpb) {
  const int j = blockIdx.x;
  const int l = threadIdx.x;
  if (j < 2304) {
#pragma unroll
    for (int k = 0; k < 12; ++k)
      we[(size_t)j * DK + l + 64 * k] = f2b(Wqkv[(size_t)j * DIMD + l + 64 * k]);
    if (l < 32) {
      int c = 768 + l;
      short v = 0;
      if (l < 4) {
        if (j < 768) v = f2b(Bq[j * 4 + l]);
      } else if (l < 8) {
        if (j >= 1536) v = f2b(Bv[(j - 1536) * 4 + (l - 4)]);
      }
      we[(size_t)j * DK + c] = v;
    }
  } else {
    const int jr = j - 2304;
#pragma unroll
    for (int k = 0; k < 12; ++k)
      wpb[(size_t)jr * DIMD + l + 64 * k] =
          f2b(Wp[(size_t)jr * DIMD + l + 64 * k]);
  }
}

// ---------------------------------------------------------------------------
// Kernel B: build xe[4096][800] = [bf16(x) | 0.25*x@Aq^T | 0.25*x@Av^T | 0]
__global__ __launch_bounds__(64)
void k_prep_x(const float* __restrict__ x, const float* __restrict__ Aq,
              const float* __restrict__ Av, short* __restrict__ xe) {
  const int i = blockIdx.x;
  const int l = threadIdx.x;
  float xv[12];
#pragma unroll
  for (int k = 0; k < 12; ++k) xv[k] = x[(size_t)i * DIMD + l + 64 * k];
#pragma unroll
  for (int k = 0; k < 12; ++k)
    xe[(size_t)i * DK + l + 64 * k] = f2b(xv[k]);
  float a8[8];
#pragma unroll
  for (int o = 0; o < 8; ++o) {
    const float* A = (o < 4) ? (Aq + o * DIMD) : (Av + (o - 4) * DIMD);
    float acc = 0.f;
#pragma unroll
    for (int k = 0; k < 12; ++k) acc = fmaf(xv[k], A[l + 64 * k], acc);
#pragma unroll
    for (int off = 32; off; off >>= 1) acc += __shfl_xor(acc, off, 64);
    a8[o] = acc;  // full sum on every lane
  }
  if (l < 32) {
    float v = 0.f;
#pragma unroll
    for (int o = 0; o < 8; ++o)
      if (l == o) v = 0.25f * a8[o];
    xe[(size_t)i * DK + 768 + l] = (l < 8) ? f2b(v) : (short)0;
  }
}

// ---------------------------------------------------------------------------
// Kernel 2: bf16 MFMA qkv GEMM over extended K=800 (LoRA folded in),
// scatter to qkvb[which][head][n][d]. 128x128 tile, BK=32, grid (18,32).
__global__ __launch_bounds__(256)
void k_qkv(const short* __restrict__ xe, const short* __restrict__ we,
           const float* __restrict__ bqkv, short* __restrict__ qkvb) {
  const int j0 = blockIdx.x * 128;
  const int i0 = blockIdx.y * 128;
  __shared__ short As[128 * 32];
  __shared__ short Bs[128 * 32];
  const int t = threadIdx.x, lane = t & 63, w = t >> 6;
  const int l15 = lane & 15, quad = lane >> 4;
  const int wm = w >> 1, wn = w & 1;

  f32x4 acc[4][4];
#pragma unroll
  for (int a = 0; a < 4; ++a)
#pragma unroll
    for (int b = 0; b < 4; ++b) acc[a][b] = (f32x4){0.f, 0.f, 0.f, 0.f};

  for (int kk = 0; kk < DK; kk += 32) {
    __syncthreads();
#pragma unroll
    for (int rep = 0; rep < 2; ++rep) {
      int c = rep * 256 + w * 64 + lane;
      gl_lds16(xe + (size_t)(i0 + (c >> 2)) * DK + kk + (c & 3) * 8,
               &As[(rep * 256 + w * 64) * 8]);
      gl_lds16(we + (size_t)(j0 + (c >> 2)) * DK + kk + (c & 3) * 8,
               &Bs[(rep * 256 + w * 64) * 8]);
    }
    __syncthreads();
    s16x8 af[4], bf[4];
#pragma unroll
    for (int mt = 0; mt < 4; ++mt)
      af[mt] = *(const s16x8*)&As[(wm * 64 + mt * 16 + l15) * 32 + quad * 8];
#pragma unroll
    for (int nt = 0; nt < 4; ++nt)
      bf[nt] = *(const s16x8*)&Bs[(wn * 64 + nt * 16 + l15) * 32 + quad * 8];
#pragma unroll
    for (int mt = 0; mt < 4; ++mt)
#pragma unroll
      for (int nt = 0; nt < 4; ++nt)
        acc[mt][nt] = MFMA16(af[mt], bf[nt], acc[mt][nt]);
  }

  const int which = j0 / DIMD;
  float bj[4]; int head[4], dd[4];
#pragma unroll
  for (int nt = 0; nt < 4; ++nt) {
    int j = j0 + wn * 64 + nt * 16 + l15;
    bj[nt] = bqkv[j];
    int jj = j - which * DIMD;
    head[nt] = jj >> 6;
    dd[nt] = jj & 63;
  }
#pragma unroll
  for (int mt = 0; mt < 4; ++mt)
#pragma unroll
    for (int r = 0; r < 4; ++r) {
      const int i = i0 + wm * 64 + mt * 16 + quad * 4 + r;
#pragma unroll
      for (int nt = 0; nt < 4; ++nt)
        qkvb[(((size_t)which * NHD + head[nt]) * NTOK + i) * HDD + dd[nt]] =
            f2b(acc[mt][nt][r] + bj[nt]);
    }
}

// ---------------------------------------------------------------------------
// Kernel 3: transpose V: qkvb[2][head][n][d] -> vtb[head][d][n]
__global__ __launch_bounds__(256)
void k_vt(const short* __restrict__ qkvb, short* __restrict__ vtb) {
  const int head = blockIdx.y;
  const int n0 = blockIdx.x * 64;
  const short* vg = qkvb + ((size_t)(2 * NHD + head)) * NTOK * HDD;
  __shared__ short T[64][68];
  const int t = threadIdx.x;
#pragma unroll
  for (int rp = 0; rp < 4; ++rp) {
    int f = t + 256 * rp;
    int n = f >> 4, c4 = (f & 15) * 4;
    *(short4*)&T[n][c4] = *(const short4*)&vg[(size_t)(n0 + n) * HDD + c4];
  }
  __syncthreads();
#pragma unroll
  for (int rp = 0; rp < 4; ++rp) {
    int f = t + 256 * rp;
    int d = f >> 4, n4 = (f & 15) * 4;
    short4 o;
    o.x = T[n4 + 0][d]; o.y = T[n4 + 1][d];
    o.z = T[n4 + 2][d]; o.w = T[n4 + 3][d];
    *(short4*)&vtb[((size_t)head * HDD + d) * NTOK + n0 + n4] = o;
  }
}

// ---------------------------------------------------------------------------
// Kernel 4: 32x32x16-MFMA flash attention, swapped operands (S^T / O^T),
// DMA double-buffered K/V staging (global_load_lds, XOR-swizzled chunks),
// one barrier per key tile. grid (64 qblocks, 12 heads), 4 waves.
//
// LDS shorts: Ks0@0, Ks1@4096, Vt0@8192, Vt1@12288 (each [64 rows][8 chunks
// of 8], chunk' = chunk ^ (row&7)), bHb@16384..20480.
// Prologue overlays in [0,16384): RW[128][72], M^T[128][64], RH[64][72].
// Epilogue overlays: obuf f32[4224]@0, psb f32@4224, tbuf shorts@8576.
__global__ __launch_bounds__(256)
void k_attn4(const short* __restrict__ qkvb, const short* __restrict__ vtb,
             const float* __restrict__ relh, const float* __restrict__ relw,
             short* __restrict__ attnb) {
  const int head = blockIdx.y;
  const int hq = blockIdx.x;
  const int n0 = hq * 64;

  __shared__ short sm[20480];
  short* smb = sm;

  const short* qg  = qkvb + (size_t)(0 * NHD + head) * NTOK * HDD;
  const short* kg  = qkvb + (size_t)(1 * NHD + head) * NTOK * HDD;
  const short* vtg = vtb + (size_t)head * HDD * NTOK;

  const int t = threadIdx.x;
  const int w = t >> 6, lane = t & 63;
  const int l31 = lane & 31, h = lane >> 5;
  const int kh = w >> 1, qh = w & 1;
  const int q = qh * 32 + l31;

  // DMA source pointers (tile 0): slot = w*64+lane covers (row, chunk^row&7)
  const int slot = w * 64 + lane;
  const int krow = slot >> 3;
  const int kcol = ((slot & 7) ^ (krow & 7)) * 8;
  const short* gK0 = kg + (size_t)krow * HDD + kcol;
  const short* gK1 = gK0 + 32 * HDD;
  const short* gV0 = vtg + (size_t)krow * NTOK + kcol;
  const short* gV1 = gV0 + (size_t)32 * NTOK;

  // Q B-fragments (persist): qb[s] = Q[q][s*16 + 8h + j]
  s16x8 qb[4];
#pragma unroll
  for (int s = 0; s < 4; ++s)
    qb[s] = *(const s16x8*)&qg[(size_t)(n0 + q) * HDD + s * 16 + 8 * h];

  // ---- prologue: RW -> overlay [0,9216) ----
#pragma unroll
  for (int rp = 0; rp < 4; ++rp) {
    int f = t + 256 * rp;
    int d = f >> 3, c = (f & 7) * 8;
    float4 v0 = make_float4(0, 0, 0, 0), v1 = v0;
    if (d < 127) {
      const float* s_ = relw + (size_t)d * HDD + c;
      v0 = *(const float4*)s_; v1 = *(const float4*)(s_ + 4);
    }
    short4 b0, b1;
    b0.x = f2b(v0.x); b0.y = f2b(v0.y); b0.z = f2b(v0.z); b0.w = f2b(v0.w);
    b1.x = f2b(v1.x); b1.y = f2b(v1.y); b1.z = f2b(v1.z); b1.w = f2b(v1.w);
    *(short4*)&smb[d * 72 + c] = b0;
    *(short4*)&smb[d * 72 + c + 4] = b1;
  }
  __syncthreads();

  // M^T = RW @ Q^T (wave covers d-tiles 2kh, 2kh+1)
  f32x16 mc0 = (f32x16)(0.f), mc1 = (f32x16)(0.f);
#pragma unroll
  for (int s = 0; s < 4; ++s) {
    s16x8 a0 = *(const s16x8*)&smb[((kh * 2) * 32 + l31) * 72 + s * 16 + 8 * h];
    s16x8 a1 = *(const s16x8*)&smb[((kh * 2 + 1) * 32 + l31) * 72 + s * 16 + 8 * h];
    mc0 = MFMA32(a0, qb[s], mc0);
    mc1 = MFMA32(a1, qb[s], mc1);
  }
  __syncthreads();
#pragma unroll
  for (int reg = 0; reg < 16; ++reg) {
    int dl = (reg & 3) + 8 * (reg >> 2) + 4 * h;
    smb[(kh * 64 + dl) * 64 + q] = f2b(mc0[reg]);
    smb[(kh * 64 + 32 + dl) * 64 + q] = f2b(mc1[reg]);
  }
  __syncthreads();

  float bwl2[16];
#pragma unroll
  for (int reg = 0; reg < 16; ++reg) {
    int kl64 = kh * 32 + (reg & 3) + 8 * (reg >> 2) + 4 * h;
    int dneed = q - kl64 + 63;  // [0,126]
    bwl2[reg] = b2f(smb[dneed * 64 + q]) * 1.44269504f;
  }
  __syncthreads();

  // RH -> overlay [0,4608)
#pragma unroll
  for (int rp = 0; rp < 2; ++rp) {
    int f = t + 256 * rp;
    int kt = f >> 3, c = (f & 7) * 8;
    const float* s_ = relh + (size_t)(hq + 63 - kt) * HDD + c;
    float4 v0 = *(const float4*)s_, v1 = *(const float4*)(s_ + 4);
    short4 b0, b1;
    b0.x = f2b(v0.x); b0.y = f2b(v0.y); b0.z = f2b(v0.z); b0.w = f2b(v0.w);
    b1.x = f2b(v1.x); b1.y = f2b(v1.y); b1.z = f2b(v1.z); b1.w = f2b(v1.w);
    *(short4*)&smb[kt * 72 + c] = b0;
    *(short4*)&smb[kt * 72 + c + 4] = b1;
  }
  __syncthreads();

  // bH^T = RH @ Q^T -> bHb @16384
  f32x16 hc = (f32x16)(0.f);
#pragma unroll
  for (int s = 0; s < 4; ++s) {
    s16x8 a = *(const s16x8*)&smb[(kh * 32 + l31) * 72 + s * 16 + 8 * h];
    hc = MFMA32(a, qb[s], hc);
  }
#pragma unroll
  for (int reg = 0; reg < 16; ++reg) {
    int ktl = kh * 32 + (reg & 3) + 8 * (reg >> 2) + 4 * h;
    smb[16384 + ktl * 64 + q] = f2b(hc[reg]);
  }
  __syncthreads();  // RH reads done; bHb published; DMA may now write [0,16384)

  // issue tile-0 DMA into buf0
  gl_lds16(gK0, smb + 0 + w * 512);
  gl_lds16(gK1, smb + 2048 + w * 512);
  gl_lds16(gV0, smb + 8192 + w * 512);
  gl_lds16(gV1, smb + 8192 + 2048 + w * 512);
  gK0 += 4096; gK1 += 4096; gV0 += 64; gV1 += 64;

  // precomputed read bases (shorts, relative to buffer start)
  int baseS[4], baseV[2];
#pragma unroll
  for (int s = 0; s < 4; ++s)
    baseS[s] = (kh * 32 + l31) * 64 + (((2 * s + h) ^ (l31 & 7)) * 8);
#pragma unroll
  for (int s2 = 0; s2 < 2; ++s2)
    baseV[s2] = l31 * 64 + (((kh * 4 + s2 * 2 + h) ^ (l31 & 7)) * 8);

  float ps = 0.f;
  f32x16 oc0 = (f32x16)(0.f), oc1 = (f32x16)(0.f);

#define ATTN_ITER(KT, KSRC, VSRC, KDST, VDST)                                  \
  {                                                                            \
    __syncthreads();                                                           \
    if ((KT) < 63) {                                                           \
      gl_lds16(gK0, smb + (KDST) + w * 512);                                   \
      gl_lds16(gK1, smb + (KDST) + 2048 + w * 512);                            \
      gl_lds16(gV0, smb + (VDST) + w * 512);                                   \
      gl_lds16(gV1, smb + (VDST) + 2048 + w * 512);                            \
      gK0 += 4096; gK1 += 4096; gV0 += 64; gV1 += 64;                          \
    }                                                                          \
    f32x16 sc_ = (f32x16)(0.f);                                                \
    _Pragma("unroll") for (int s = 0; s < 4; ++s) {                            \
      s16x8 a = *(const s16x8*)&smb[(KSRC) + baseS[s]];                        \
      sc_ = MFMA32(a, qb[s], sc_);                                             \
    }                                                                          \
    float bhl2 = b2f(smb[16384 + (KT) * 64 + q]) * 1.44269504f;                \
    float sv[16];                                                              \
    _Pragma("unroll") for (int reg = 0; reg < 16; ++reg) {                     \
      sv[reg] = exp2f(fmaf(0.18033688f, sc_[reg], bhl2 + bwl2[reg]));          \
      ps += sv[reg];                                                           \
    }                                                                          \
    unsigned pk[8], sw[8];                                                     \
    _Pragma("unroll") for (int i = 0; i < 8; ++i) {                            \
      int rl = 4 * (i >> 1) + 2 * (i & 1);                                     \
      pk[i] = __builtin_amdgcn_perm(__float_as_uint(sv[rl + 1]),               \
                                    __float_as_uint(sv[rl]), 0x07060302u);     \
    }                                                                          \
    _Pragma("unroll") for (int i = 0; i < 8; ++i)                              \
      sw[i] = (unsigned)__shfl_xor((int)pk[i], 32, 64);                        \
    _Pragma("unroll") for (int s2 = 0; s2 < 2; ++s2) {                         \
      union { unsigned u[4]; s16x8 v; } B;                                     \
      B.u[0] = h ? sw[4 * s2 + 2] : pk[4 * s2 + 0];                            \
      B.u[1] = h ? sw[4 * s2 + 3] : pk[4 * s2 + 1];                            \
      B.u[2] = h ? pk[4 * s2 + 2] : sw[4 * s2 + 0];                            \
      B.u[3] = h ? pk[4 * s2 + 3] : sw[4 * s2 + 1];                            \
      s16x8 a0 = *(const s16x8*)&smb[(VSRC) + baseV[s2]];                      \
      s16x8 a1 = *(const s16x8*)&smb[(VSRC) + 2048 + baseV[s2]];               \
      oc0 = MFMA32(a0, B.v, oc0);                                              \
      oc1 = MFMA32(a1, B.v, oc1);                                              \
    }                                                                          \
  }

  for (int k2 = 0; k2 < 32; ++k2) {
    ATTN_ITER(2 * k2, 0, 8192, 4096, 12288);
    ATTN_ITER(2 * k2 + 1, 4096, 12288, 0, 8192);
  }
#undef ATTN_ITER

  // ---- epilogue: combine kh halves, normalize, transpose, store ----
  __syncthreads();
  float* obuf = (float*)smb;          // [64][66] floats @0
  float* psb  = (float*)smb + 4224;   // 64 floats
  short* tbuf = smb + 8576;           // [64][66] shorts
  ps += __shfl_xor(ps, 32, 64);
  if (kh == 1) {
#pragma unroll
    for (int reg = 0; reg < 16; ++reg) {
      int dl = (reg & 3) + 8 * (reg >> 2) + 4 * h;
      obuf[dl * 66 + q] = oc0[reg];
      obuf[(32 + dl) * 66 + q] = oc1[reg];
    }
    if (lane < 32) psb[q] = ps;
  }
  __syncthreads();
  if (kh == 0) {
    float inv = 1.f / (ps + psb[q]);
#pragma unroll
    for (int reg = 0; reg < 16; ++reg) {
      int dl = (reg & 3) + 8 * (reg >> 2) + 4 * h;
      tbuf[dl * 66 + q] = f2b((oc0[reg] + obuf[dl * 66 + q]) * inv);
      tbuf[(32 + dl) * 66 + q] = f2b((oc1[reg] + obuf[(32 + dl) * 66 + q]) * inv);
    }
  }
  __syncthreads();
  {
    int qq = t >> 2, seg = t & 3;
    unsigned wds[8];
#pragma unroll
    for (int m = 0; m < 8; ++m) {
      unsigned lo = (unsigned short)tbuf[(seg * 16 + 2 * m) * 66 + qq];
      unsigned hi = (unsigned short)tbuf[(seg * 16 + 2 * m + 1) * 66 + qq];
      wds[m] = lo | (hi << 16);
    }
    short* dst = attnb + (size_t)(n0 + qq) * DIMD + head * 64 + seg * 16;
    *(int4*)dst = *(int4*)&wds[0];
    *(int4*)(dst + 8) = *(int4*)&wds[4];
  }
}

// ---------------------------------------------------------------------------
// Kernel 5: bf16 MFMA proj: out = attn @ Wp^T + bp (fp32 out)
__global__ __launch_bounds__(256)
void k_proj(const short* __restrict__ ab, const short* __restrict__ wpb,
            const float* __restrict__ bp, float* __restrict__ out) {
  const int j0 = blockIdx.x * 64;
  const int i0 = blockIdx.y * 128;
  __shared__ short As[128 * 32];
  __shared__ short Bs[64 * 32];
  const int t = threadIdx.x, lane = t & 63, w = t >> 6;
  const int l15 = lane & 15, quad = lane >> 4;
  const int wm = w >> 1, wn = w & 1;

  f32x4 acc[4][2];
#pragma unroll
  for (int a = 0; a < 4; ++a)
#pragma unroll
    for (int b = 0; b < 2; ++b) acc[a][b] = (f32x4){0.f, 0.f, 0.f, 0.f};

  for (int kk = 0; kk < DIMD; kk += 32) {
    __syncthreads();
#pragma unroll
    for (int rep = 0; rep < 2; ++rep) {
      int c = rep * 256 + w * 64 + lane;
      gl_lds16(ab + (size_t)(i0 + (c >> 2)) * DIMD + kk + (c & 3) * 8,
               &As[(rep * 256 + w * 64) * 8]);
    }
    {
      gl_lds16(wpb + (size_t)(j0 + ((w * 64 + lane) >> 2)) * DIMD + kk +
                   ((w * 64 + lane) & 3) * 8,
               &Bs[(w * 64) * 8]);
    }
    __syncthreads();
    s16x8 af[4], bf[2];
#pragma unroll
    for (int mt = 0; mt < 4; ++mt)
      af[mt] = *(const s16x8*)&As[(wm * 64 + mt * 16 + l15) * 32 + quad * 8];
#pragma unroll
    for (int nt = 0; nt < 2; ++nt)
      bf[nt] = *(const s16x8*)&Bs[(wn * 32 + nt * 16 + l15) * 32 + quad * 8];
#pragma unroll
    for (int mt = 0; mt < 4; ++mt)
#pragma unroll
      for (int nt = 0; nt < 2; ++nt)
        acc[mt][nt] = MFMA16(af[mt], bf[nt], acc[mt][nt]);
  }

#pragma unroll
  for (int mt = 0; mt < 4; ++mt)
#pragma unroll
    for (int r = 0; r < 4; ++r) {
      const int i = i0 + wm * 64 + mt * 16 + quad * 4 + r;
#pragma unroll
      for (int nt = 0; nt < 2; ++nt) {
        const int j = j0 + wn * 32 + nt * 16 + l15;
        out[(size_t)i * DIMD + j] = acc[mt][nt][r] + bp[j];
      }
    }
}

// ---------------------------------------------------------------------------
extern "C" void kernel_launch(void* const* d_in, const int* in_sizes, int n_in,
                              void* d_out, int out_size, void* d_ws, size_t ws_size,
                              hipStream_t stream) {
  (void)in_sizes; (void)n_in; (void)out_size; (void)ws_size;
  const float* x    = (const float*)d_in[0];
  const float* Wqkv = (const float*)d_in[1];
  const float* bqkv = (const float*)d_in[2];
  const float* Aq   = (const float*)d_in[3];
  const float* Bq   = (const float*)d_in[4];
  const float* Av   = (const float*)d_in[5];
  const float* Bv   = (const float*)d_in[6];
  const float* relh = (const float*)d_in[7];
  const float* relw = (const float*)d_in[8];
  const float* Wp   = (const float*)d_in[9];
  const float* bp   = (const float*)d_in[10];
  float* out = (float*)d_out;

  float* ws = (float*)d_ws;
  short* xe    = (short*)(ws);
  short* we    = (short*)(ws + 1638400);
  short* wpb   = (short*)(ws + 2560000);
  short* qkvb  = (short*)(ws + 2854912);
  short* vtb   = (short*)(ws + 7573504);
  short* attnb = (short*)(ws + 9146368);

  k_prep_w<<<dim3(3072), dim3(64), 0, stream>>>(Wqkv, Bq, Bv, Wp, we, wpb);
  k_prep_x<<<dim3(NTOK), dim3(64), 0, stream>>>(x, Aq, Av, xe);
  k_qkv<<<dim3(18, 32), dim3(256), 0, stream>>>(xe, we, bqkv, qkvb);
  k_vt<<<dim3(64, NHD), dim3(256), 0, stream>>>(qkvb, vtb);
  k_attn4<<<dim3(64, NHD), dim3(256), 0, stream>>>(qkvb, vtb, relh, relw, attnb);
  k_proj<<<dim3(12, 32), dim3(256), 0, stream>>>(attnb, wpb, bp, out);
}

// Round 7
// 257.142 us; speedup vs baseline: 1.0748x; 1.0748x over previous
//
#include <hip/hip_runtime.h>

// x:(1,64,64,768) -> n=4096 tokens, DIM=768, 12 heads x 64 dim
#define NTOK 4096
#define DIMD 768
#define NHD  12
#define HDD  64
#define DK   800   // extended K: 768 x | 4 lora-q | 4 lora-v | 24 zero

typedef float  f32x4  __attribute__((ext_vector_type(4)));
typedef float  f32x16 __attribute__((ext_vector_type(16)));
typedef short  s16x8  __attribute__((ext_vector_type(8)));

#define MFMA16(a, b, c) __builtin_amdgcn_mfma_f32_16x16x32_bf16(a, b, c, 0, 0, 0)
#define MFMA32(a, b, c) __builtin_amdgcn_mfma_f32_32x32x16_bf16(a, b, c, 0, 0, 0)

__device__ inline short f2b(float f) {  // fp32 -> bf16 RNE
  unsigned u = __float_as_uint(f);
  u += 0x7FFFu + ((u >> 16) & 1u);
  return (short)(u >> 16);
}
__device__ inline float b2f(short s) {
  return __uint_as_float(((unsigned)(unsigned short)s) << 16);
}
__device__ inline void gl_lds16(const short* g, short* l) {
  __builtin_amdgcn_global_load_lds(
      (const __attribute__((address_space(1))) unsigned int*)g,
      (__attribute__((address_space(3))) unsigned int*)l, 16, 0, 0);
}

// ws layout (float units):
//   xe    @0         bf16 [4096][800]
//   we    @1638400   bf16 [2304][800]
//   wpb   @2560000   bf16 [768][768]
//   qkvb  @2854912   bf16 [3][12][4096][64]
//   vtb   @7573504   bf16 [12][64][4096]
//   attnb @9146368   bf16 [4096][768]

// ---------------------------------------------------------------------------
// Kernel A: build extended weights we[2304][800] and wpb[768][768] (bf16)
__global__ __launch_bounds__(64)
void k_prep_w(const float* __restrict__ Wqkv, const float* __restrict__ Bq,
              const float* __restrict__ Bv, const float* __restrict__ Wp,
              short* __restrict__ we, short* __restrict__ wpb) {
  const int j = blockIdx.x;
  const int l = threadIdx.x;
  if (j < 2304) {
#pragma unroll
    for (int k = 0; k < 12; ++k)
      we[(size_t)j * DK + l + 64 * k] = f2b(Wqkv[(size_t)j * DIMD + l + 64 * k]);
    if (l < 32) {
      int c = 768 + l;
      short v = 0;
      if (l < 4) {
        if (j < 768) v = f2b(Bq[j * 4 + l]);
      } else if (l < 8) {
        if (j >= 1536) v = f2b(Bv[(j - 1536) * 4 + (l - 4)]);
      }
      we[(size_t)j * DK + c] = v;
    }
  } else {
    const int jr = j - 2304;
#pragma unroll
    for (int k = 0; k < 12; ++k)
      wpb[(size_t)jr * DIMD + l + 64 * k] =
          f2b(Wp[(size_t)jr * DIMD + l + 64 * k]);
  }
}

// ---------------------------------------------------------------------------
// Kernel B: build xe[4096][800] = [bf16(x) | 0.25*x@Aq^T | 0.25*x@Av^T | 0]
__global__ __launch_bounds__(64)
void k_prep_x(const float* __restrict__ x, const float* __restrict__ Aq,
              const float* __restrict__ Av, short* __restrict__ xe) {
  const int i = blockIdx.x;
  const int l = threadIdx.x;
  float xv[12];
#pragma unroll
  for (int k = 0; k < 12; ++k) xv[k] = x[(size_t)i * DIMD + l + 64 * k];
#pragma unroll
  for (int k = 0; k < 12; ++k)
    xe[(size_t)i * DK + l + 64 * k] = f2b(xv[k]);
  float a8[8];
#pragma unroll
  for (int o = 0; o < 8; ++o) {
    const float* A = (o < 4) ? (Aq + o * DIMD) : (Av + (o - 4) * DIMD);
    float acc = 0.f;
#pragma unroll
    for (int k = 0; k < 12; ++k) acc = fmaf(xv[k], A[l + 64 * k], acc);
#pragma unroll
    for (int off = 32; off; off >>= 1) acc += __shfl_xor(acc, off, 64);
    a8[o] = acc;
  }
  if (l < 32) {
    float v = 0.f;
#pragma unroll
    for (int o = 0; o < 8; ++o)
      if (l == o) v = 0.25f * a8[o];
    xe[(size_t)i * DK + 768 + l] = (l < 8) ? f2b(v) : (short)0;
  }
}

// ---------------------------------------------------------------------------
// Kernel 2: bf16 MFMA qkv GEMM over extended K=800 (LoRA folded in),
// LDS-staged coalesced epilogue, scatter to qkvb[which][head][n][d].
__global__ __launch_bounds__(256)
void k_qkv(const short* __restrict__ xe, const short* __restrict__ we,
           const float* __restrict__ bqkv, short* __restrict__ qkvb) {
  const int j0 = blockIdx.x * 128;
  const int i0 = blockIdx.y * 128;
  __shared__ short As[128 * 32];
  __shared__ short Bs[128 * 32];
  __shared__ short Cs[128 * 130];
  const int t = threadIdx.x, lane = t & 63, w = t >> 6;
  const int l15 = lane & 15, quad = lane >> 4;
  const int wm = w >> 1, wn = w & 1;

  f32x4 acc[4][4];
#pragma unroll
  for (int a = 0; a < 4; ++a)
#pragma unroll
    for (int b = 0; b < 4; ++b) acc[a][b] = (f32x4){0.f, 0.f, 0.f, 0.f};

  for (int kk = 0; kk < DK; kk += 32) {
    __syncthreads();
#pragma unroll
    for (int rep = 0; rep < 2; ++rep) {
      int c = rep * 256 + w * 64 + lane;
      gl_lds16(xe + (size_t)(i0 + (c >> 2)) * DK + kk + (c & 3) * 8,
               &As[(rep * 256 + w * 64) * 8]);
      gl_lds16(we + (size_t)(j0 + (c >> 2)) * DK + kk + (c & 3) * 8,
               &Bs[(rep * 256 + w * 64) * 8]);
    }
    __syncthreads();
    s16x8 af[4], bf[4];
#pragma unroll
    for (int mt = 0; mt < 4; ++mt)
      af[mt] = *(const s16x8*)&As[(wm * 64 + mt * 16 + l15) * 32 + quad * 8];
#pragma unroll
    for (int nt = 0; nt < 4; ++nt)
      bf[nt] = *(const s16x8*)&Bs[(wn * 64 + nt * 16 + l15) * 32 + quad * 8];
#pragma unroll
    for (int mt = 0; mt < 4; ++mt)
#pragma unroll
      for (int nt = 0; nt < 4; ++nt)
        acc[mt][nt] = MFMA16(af[mt], bf[nt], acc[mt][nt]);
  }

  const int which = j0 / DIMD;
  float bj[4];
#pragma unroll
  for (int nt = 0; nt < 4; ++nt) bj[nt] = bqkv[j0 + wn * 64 + nt * 16 + l15];

  // stage C (bf16, +bias) into LDS, then coalesced 16B stores
#pragma unroll
  for (int mt = 0; mt < 4; ++mt)
#pragma unroll
    for (int r = 0; r < 4; ++r) {
      const int row = wm * 64 + mt * 16 + quad * 4 + r;
#pragma unroll
      for (int nt = 0; nt < 4; ++nt) {
        const int col = wn * 64 + nt * 16 + l15;
        Cs[row * 130 + col] = f2b(acc[mt][nt][r] + bj[nt]);
      }
    }
  __syncthreads();
  const int base_head = (j0 - which * DIMD) >> 6;
#pragma unroll
  for (int rp = 0; rp < 8; ++rp) {
    int f = t + 256 * rp;            // 0..2047
    int row = f >> 4, ch = f & 15;   // 16 chunks of 8 shorts per row
    int head = base_head + (ch >> 3);
    int ddb = (ch & 7) * 8;
    s16x8 v = *(const s16x8*)&Cs[row * 130 + ch * 8];
    *(s16x8*)&qkvb[(((size_t)which * NHD + head) * NTOK + i0 + row) * HDD + ddb] = v;
  }
}

// ---------------------------------------------------------------------------
// Kernel 3: transpose V: qkvb[2][head][n][d] -> vtb[head][d][n]
__global__ __launch_bounds__(256)
void k_vt(const short* __restrict__ qkvb, short* __restrict__ vtb) {
  const int head = blockIdx.y;
  const int n0 = blockIdx.x * 64;
  const short* vg = qkvb + ((size_t)(2 * NHD + head)) * NTOK * HDD;
  __shared__ short T[64][68];
  const int t = threadIdx.x;
#pragma unroll
  for (int rp = 0; rp < 4; ++rp) {
    int f = t + 256 * rp;
    int n = f >> 4, c4 = (f & 15) * 4;
    *(short4*)&T[n][c4] = *(const short4*)&vg[(size_t)(n0 + n) * HDD + c4];
  }
  __syncthreads();
#pragma unroll
  for (int rp = 0; rp < 4; ++rp) {
    int f = t + 256 * rp;
    int d = f >> 4, n4 = (f & 15) * 4;
    short4 o;
    o.x = T[n4 + 0][d]; o.y = T[n4 + 1][d];
    o.z = T[n4 + 2][d]; o.w = T[n4 + 3][d];
    *(short4*)&vtb[((size_t)head * HDD + d) * NTOK + n0 + n4] = o;
  }
}

// ---------------------------------------------------------------------------
// Kernel 4: 32x32x16-MFMA flash attention, swapped operands (S^T / O^T),
// DMA double-buffered staging + K-FRAGMENT REGISTER PREFETCH (frags for tile
// kt+1 read during compute of kt -> S-MFMAs start from registers at iter top).
// One barrier per key tile. grid (64 qblocks, 12 heads), 4 waves.
// LDS shorts: K0@0, K1@4096, V0@8192, V1@12288, bHb@16384..20480.
__global__ __launch_bounds__(256)
void k_attn5(const short* __restrict__ qkvb, const short* __restrict__ vtb,
             const float* __restrict__ relh, const float* __restrict__ relw,
             short* __restrict__ attnb) {
  const int head = blockIdx.y;
  const int hq = blockIdx.x;
  const int n0 = hq * 64;

  __shared__ short sm[20480];
  short* smb = sm;

  const short* qg  = qkvb + (size_t)(0 * NHD + head) * NTOK * HDD;
  const short* kg  = qkvb + (size_t)(1 * NHD + head) * NTOK * HDD;
  const short* vtg = vtb + (size_t)head * HDD * NTOK;

  const int t = threadIdx.x;
  const int w = t >> 6, lane = t & 63;
  const int l31 = lane & 31, h = lane >> 5;
  const int kh = w >> 1, qh = w & 1;
  const int q = qh * 32 + l31;

  // DMA slot: (row, chunk ^ (row&7))
  const int slot = w * 64 + lane;
  const int krow = slot >> 3;
  const int kcol = ((slot & 7) ^ (krow & 7)) * 8;
  const short* gK0 = kg + (size_t)krow * HDD + kcol;
  const short* gK1 = gK0 + 32 * HDD;
  const short* gV0 = vtg + (size_t)krow * NTOK + kcol;
  const short* gV1 = gV0 + (size_t)32 * NTOK;

  // Q B-fragments (persist)
  s16x8 qb[4];
#pragma unroll
  for (int s = 0; s < 4; ++s)
    qb[s] = *(const s16x8*)&qg[(size_t)(n0 + q) * HDD + s * 16 + 8 * h];

  // ---- prologue: RW -> overlay ----
#pragma unroll
  for (int rp = 0; rp < 4; ++rp) {
    int f = t + 256 * rp;
    int d = f >> 3, c = (f & 7) * 8;
    float4 v0 = make_float4(0, 0, 0, 0), v1 = v0;
    if (d < 127) {
      const float* s_ = relw + (size_t)d * HDD + c;
      v0 = *(const float4*)s_; v1 = *(const float4*)(s_ + 4);
    }
    short4 b0, b1;
    b0.x = f2b(v0.x); b0.y = f2b(v0.y); b0.z = f2b(v0.z); b0.w = f2b(v0.w);
    b1.x = f2b(v1.x); b1.y = f2b(v1.y); b1.z = f2b(v1.z); b1.w = f2b(v1.w);
    *(short4*)&smb[d * 72 + c] = b0;
    *(short4*)&smb[d * 72 + c + 4] = b1;
  }
  __syncthreads();

  // M^T = RW @ Q^T
  f32x16 mc0 = (f32x16)(0.f), mc1 = (f32x16)(0.f);
#pragma unroll
  for (int s = 0; s < 4; ++s) {
    s16x8 a0 = *(const s16x8*)&smb[((kh * 2) * 32 + l31) * 72 + s * 16 + 8 * h];
    s16x8 a1 = *(const s16x8*)&smb[((kh * 2 + 1) * 32 + l31) * 72 + s * 16 + 8 * h];
    mc0 = MFMA32(a0, qb[s], mc0);
    mc1 = MFMA32(a1, qb[s], mc1);
  }
  __syncthreads();
#pragma unroll
  for (int reg = 0; reg < 16; ++reg) {
    int dl = (reg & 3) + 8 * (reg >> 2) + 4 * h;
    smb[(kh * 64 + dl) * 64 + q] = f2b(mc0[reg]);
    smb[(kh * 64 + 32 + dl) * 64 + q] = f2b(mc1[reg]);
  }
  __syncthreads();

  float bwl2[16];
#pragma unroll
  for (int reg = 0; reg < 16; ++reg) {
    int kl64 = kh * 32 + (reg & 3) + 8 * (reg >> 2) + 4 * h;
    int dneed = q - kl64 + 63;  // [0,126]
    bwl2[reg] = b2f(smb[dneed * 64 + q]) * 1.44269504f;
  }
  __syncthreads();

  // RH -> overlay
#pragma unroll
  for (int rp = 0; rp < 2; ++rp) {
    int f = t + 256 * rp;
    int kt = f >> 3, c = (f & 7) * 8;
    const float* s_ = relh + (size_t)(hq + 63 - kt) * HDD + c;
    float4 v0 = *(const float4*)s_, v1 = *(const float4*)(s_ + 4);
    short4 b0, b1;
    b0.x = f2b(v0.x); b0.y = f2b(v0.y); b0.z = f2b(v0.z); b0.w = f2b(v0.w);
    b1.x = f2b(v1.x); b1.y = f2b(v1.y); b1.z = f2b(v1.z); b1.w = f2b(v1.w);
    *(short4*)&smb[kt * 72 + c] = b0;
    *(short4*)&smb[kt * 72 + c + 4] = b1;
  }
  __syncthreads();

  // bH^T = RH @ Q^T -> bHb @16384
  f32x16 hc = (f32x16)(0.f);
#pragma unroll
  for (int s = 0; s < 4; ++s) {
    s16x8 a = *(const s16x8*)&smb[(kh * 32 + l31) * 72 + s * 16 + 8 * h];
    hc = MFMA32(a, qb[s], hc);
  }
#pragma unroll
  for (int reg = 0; reg < 16; ++reg) {
    int ktl = kh * 32 + (reg & 3) + 8 * (reg >> 2) + 4 * h;
    smb[16384 + ktl * 64 + q] = f2b(hc[reg]);
  }
  __syncthreads();  // RH reads done; bHb published; DMA may write [0,16384)

  // bootstrap DMA: K(0)->K0, K(1)->K1, V(0)->V0
  gl_lds16(gK0, smb + 0 + w * 512);
  gl_lds16(gK1, smb + 2048 + w * 512);
  gK0 += 4096; gK1 += 4096;
  gl_lds16(gK0, smb + 4096 + w * 512);
  gl_lds16(gK1, smb + 4096 + 2048 + w * 512);
  gK0 += 4096; gK1 += 4096;                  // -> tile 2
  gl_lds16(gV0, smb + 8192 + w * 512);
  gl_lds16(gV1, smb + 8192 + 2048 + w * 512);
  gV0 += 64; gV1 += 64;                      // -> tile 1
  __syncthreads();                           // drain: K0,K1,V0 resident

  // read bases
  int baseS[4], baseV[2];
#pragma unroll
  for (int s = 0; s < 4; ++s)
    baseS[s] = (kh * 32 + l31) * 64 + (((2 * s + h) ^ (l31 & 7)) * 8);
#pragma unroll
  for (int s2 = 0; s2 < 2; ++s2)
    baseV[s2] = l31 * 64 + (((kh * 4 + s2 * 2 + h) ^ (l31 & 7)) * 8);

  // initial frags + bias
  s16x8 ka0[4], ka1[4];
#pragma unroll
  for (int s = 0; s < 4; ++s) ka0[s] = *(const s16x8*)&smb[0 + baseS[s]];
  float bh_cur = b2f(smb[16384 + q]) * 1.44269504f;
  __syncthreads();  // order frag reads vs first iter's DMA into K0's sibling

  float ps = 0.f;
  f32x16 oc0 = (f32x16)(0.f), oc1 = (f32x16)(0.f);

#define ATTN_ITER(KT, KAc, KAn, KDST, KNXT, VCUR, VNXT)                        \
  {                                                                            \
    if ((KT) < 62) {                                                           \
      gl_lds16(gK0, smb + (KDST) + w * 512);                                   \
      gl_lds16(gK1, smb + (KDST) + 2048 + w * 512);                            \
      gK0 += 4096; gK1 += 4096;                                                \
    }                                                                          \
    if ((KT) < 63) {                                                           \
      gl_lds16(gV0, smb + (VNXT) + w * 512);                                   \
      gl_lds16(gV1, smb + (VNXT) + 2048 + w * 512);                            \
      gV0 += 64; gV1 += 64;                                                    \
    }                                                                          \
    float bhn = 0.f;                                                           \
    if ((KT) < 63) {                                                           \
      _Pragma("unroll") for (int s = 0; s < 4; ++s)                            \
          KAn[s] = *(const s16x8*)&smb[(KNXT) + baseS[s]];                     \
      bhn = b2f(smb[16384 + ((KT) + 1) * 64 + q]) * 1.44269504f;               \
    }                                                                          \
    s16x8 va[4];                                                               \
    _Pragma("unroll") for (int s2 = 0; s2 < 2; ++s2) {                         \
      va[s2 * 2 + 0] = *(const s16x8*)&smb[(VCUR) + baseV[s2]];                \
      va[s2 * 2 + 1] = *(const s16x8*)&smb[(VCUR) + 2048 + baseV[s2]];         \
    }                                                                          \
    f32x16 sc_ = (f32x16)(0.f);                                                \
    _Pragma("unroll") for (int s = 0; s < 4; ++s)                              \
        sc_ = MFMA32(KAc[s], qb[s], sc_);                                      \
    float sv[16];                                                              \
    _Pragma("unroll") for (int reg = 0; reg < 16; ++reg) {                     \
      sv[reg] = exp2f(fmaf(0.18033688f, sc_[reg], bh_cur + bwl2[reg]));        \
      ps += sv[reg];                                                           \
    }                                                                          \
    unsigned pk[8], sw[8];                                                     \
    _Pragma("unroll") for (int i = 0; i < 8; ++i) {                            \
      int rl = 4 * (i >> 1) + 2 * (i & 1);                                     \
      pk[i] = __builtin_amdgcn_perm(__float_as_uint(sv[rl + 1]),               \
                                    __float_as_uint(sv[rl]), 0x07060302u);     \
    }                                                                          \
    _Pragma("unroll") for (int i = 0; i < 8; ++i)                              \
      sw[i] = (unsigned)__shfl_xor((int)pk[i], 32, 64);                        \
    _Pragma("unroll") for (int s2 = 0; s2 < 2; ++s2) {                         \
      union { unsigned u[4]; s16x8 v; } B;                                     \
      B.u[0] = h ? sw[4 * s2 + 2] : pk[4 * s2 + 0];                            \
      B.u[1] = h ? sw[4 * s2 + 3] : pk[4 * s2 + 1];                            \
      B.u[2] = h ? pk[4 * s2 + 2] : sw[4 * s2 + 0];                            \
      B.u[3] = h ? pk[4 * s2 + 3] : sw[4 * s2 + 1];                            \
      oc0 = MFMA32(va[s2 * 2 + 0], B.v, oc0);                                  \
      oc1 = MFMA32(va[s2 * 2 + 1], B.v, oc1);                                  \
    }                                                                          \
    bh_cur = bhn;                                                              \
    __syncthreads();                                                           \
  }

  for (int k2 = 0; k2 < 32; ++k2) {
    ATTN_ITER(2 * k2,     ka0, ka1, 0,    4096, 8192,  12288);
    ATTN_ITER(2 * k2 + 1, ka1, ka0, 4096, 0,    12288, 8192);
  }
#undef ATTN_ITER

  // ---- epilogue: combine kh halves, normalize, transpose, store ----
  float* obuf = (float*)smb;          // [64][66] floats @0
  float* psb  = (float*)smb + 4224;
  short* tbuf = smb + 8576;           // [64][66] shorts
  ps += __shfl_xor(ps, 32, 64);
  if (kh == 1) {
#pragma unroll
    for (int reg = 0; reg < 16; ++reg) {
      int dl = (reg & 3) + 8 * (reg >> 2) + 4 * h;
      obuf[dl * 66 + q] = oc0[reg];
      obuf[(32 + dl) * 66 + q] = oc1[reg];
    }
    if (lane < 32) psb[q] = ps;
  }
  __syncthreads();
  if (kh == 0) {
    float inv = 1.f / (ps + psb[q]);
#pragma unroll
    for (int reg = 0; reg < 16; ++reg) {
      int dl = (reg & 3) + 8 * (reg >> 2) + 4 * h;
      tbuf[dl * 66 + q] = f2b((oc0[reg] + obuf[dl * 66 + q]) * inv);
      tbuf[(32 + dl) * 66 + q] = f2b((oc1[reg] + obuf[(32 + dl) * 66 + q]) * inv);
    }
  }
  __syncthreads();
  {
    int qq = t >> 2, seg = t & 3;
    unsigned wds[8];
#pragma unroll
    for (int m = 0; m < 8; ++m) {
      unsigned lo = (unsigned short)tbuf[(seg * 16 + 2 * m) * 66 + qq];
      unsigned hi = (unsigned short)tbuf[(seg * 16 + 2 * m + 1) * 66 + qq];
      wds[m] = lo | (hi << 16);
    }
    short* dst = attnb + (size_t)(n0 + qq) * DIMD + head * 64 + seg * 16;
    *(int4*)dst = *(int4*)&wds[0];
    *(int4*)(dst + 8) = *(int4*)&wds[4];
  }
}

// ---------------------------------------------------------------------------
// Kernel 5: bf16 MFMA proj: out = attn @ Wp^T + bp (fp32 out)
__global__ __launch_bounds__(256)
void k_proj(const short* __restrict__ ab, const short* __restrict__ wpb,
            const float* __restrict__ bp, float* __restrict__ out) {
  const int j0 = blockIdx.x * 64;
  const int i0 = blockIdx.y * 128;
  __shared__ short As[128 * 32];
  __shared__ short Bs[64 * 32];
  const int t = threadIdx.x, lane = t & 63, w = t >> 6;
  const int l15 = lane & 15, quad = lane >> 4;
  const int wm = w >> 1, wn = w & 1;

  f32x4 acc[4][2];
#pragma unroll
  for (int a = 0; a < 4; ++a)
#pragma unroll
    for (int b = 0; b < 2; ++b) acc[a][b] = (f32x4){0.f, 0.f, 0.f, 0.f};

  for (int kk = 0; kk < DIMD; kk += 32) {
    __syncthreads();
#pragma unroll
    for (int rep = 0; rep < 2; ++rep) {
      int c = rep * 256 + w * 64 + lane;
      gl_lds16(ab + (size_t)(i0 + (c >> 2)) * DIMD + kk + (c & 3) * 8,
               &As[(rep * 256 + w * 64) * 8]);
    }
    {
      gl_lds16(wpb + (size_t)(j0 + ((w * 64 + lane) >> 2)) * DIMD + kk +
                   ((w * 64 + lane) & 3) * 8,
               &Bs[(w * 64) * 8]);
    }
    __syncthreads();
    s16x8 af[4], bf[2];
#pragma unroll
    for (int mt = 0; mt < 4; ++mt)
      af[mt] = *(const s16x8*)&As[(wm * 64 + mt * 16 + l15) * 32 + quad * 8];
#pragma unroll
    for (int nt = 0; nt < 2; ++nt)
      bf[nt] = *(const s16x8*)&Bs[(wn * 32 + nt * 16 + l15) * 32 + quad * 8];
#pragma unroll
    for (int mt = 0; mt < 4; ++mt)
#pragma unroll
      for (int nt = 0; nt < 2; ++nt)
        acc[mt][nt] = MFMA16(af[mt], bf[nt], acc[mt][nt]);
  }

#pragma unroll
  for (int mt = 0; mt < 4; ++mt)
#pragma unroll
    for (int r = 0; r < 4; ++r) {
      const int i = i0 + wm * 64 + mt * 16 + quad * 4 + r;
#pragma unroll
      for (int nt = 0; nt < 2; ++nt) {
        const int j = j0 + wn * 32 + nt * 16 + l15;
        out[(size_t)i * DIMD + j] = acc[mt][nt][r] + bp[j];
      }
    }
}

// ---------------------------------------------------------------------------
extern "C" void kernel_launch(void* const* d_in, const int* in_sizes, int n_in,
                              void* d_out, int out_size, void* d_ws, size_t ws_size,
                              hipStream_t stream) {
  (void)in_sizes; (void)n_in; (void)out_size; (void)ws_size;
  const float* x    = (const float*)d_in[0];
  const float* Wqkv = (const float*)d_in[1];
  const float* bqkv = (const float*)d_in[2];
  const float* Aq   = (const float*)d_in[3];
  const float* Bq   = (const float*)d_in[4];
  const float* Av   = (const float*)d_in[5];
  const float* Bv   = (const float*)d_in[6];
  const float* relh = (const float*)d_in[7];
  const float* relw = (const float*)d_in[8];
  const float* Wp   = (const float*)d_in[9];
  const float* bp   = (const float*)d_in[10];
  float* out = (float*)d_out;

  float* ws = (float*)d_ws;
  short* xe    = (short*)(ws);
  short* we    = (short*)(ws + 1638400);
  short* wpb   = (short*)(ws + 2560000);
  short* qkvb  = (short*)(ws + 2854912);
  short* vtb   = (short*)(ws + 7573504);
  short* attnb = (short*)(ws + 9146368);

  k_prep_w<<<dim3(3072), dim3(64), 0, stream>>>(Wqkv, Bq, Bv, Wp, we, wpb);
  k_prep_x<<<dim3(NTOK), dim3(64), 0, stream>>>(x, Aq, Av, xe);
  k_qkv<<<dim3(18, 32), dim3(256), 0, stream>>>(xe, we, bqkv, qkvb);
  k_vt<<<dim3(64, NHD), dim3(256), 0, stream>>>(qkvb, vtb);
  k_attn5<<<dim3(64, NHD), dim3(256), 0, stream>>>(qkvb, vtb, relh, relw, attnb);
  k_proj<<<dim3(12, 32), dim3(256), 0, stream>>>(attnb, wpb, bp, out);
}

// Round 8
// 242.848 us; speedup vs baseline: 1.1380x; 1.0589x over previous
//
#include <hip/hip_runtime.h>

// x:(1,64,64,768) -> n=4096 tokens, DIM=768, 12 heads x 64 dim
#define NTOK 4096
#define DIMD 768
#define NHD  12
#define HDD  64
#define DK   800   // extended K: 768 x | 4 lora-q | 4 lora-v | 24 zero

typedef float  f32x4  __attribute__((ext_vector_type(4)));
typedef float  f32x16 __attribute__((ext_vector_type(16)));
typedef short  s16x8  __attribute__((ext_vector_type(8)));

#define MFMA16(a, b, c) __builtin_amdgcn_mfma_f32_16x16x32_bf16(a, b, c, 0, 0, 0)
#define MFMA32(a, b, c) __builtin_amdgcn_mfma_f32_32x32x16_bf16(a, b, c, 0, 0, 0)

__device__ inline short f2b(float f) {  // fp32 -> bf16 RNE
  unsigned u = __float_as_uint(f);
  u += 0x7FFFu + ((u >> 16) & 1u);
  return (short)(u >> 16);
}
__device__ inline float b2f(short s) {
  return __uint_as_float(((unsigned)(unsigned short)s) << 16);
}
__device__ inline void gl_lds16(const short* g, short* l) {
  __builtin_amdgcn_global_load_lds(
      (const __attribute__((address_space(1))) unsigned int*)g,
      (__attribute__((address_space(3))) unsigned int*)l, 16, 0, 0);
}

// ws layout (float units):
//   xe    @0         bf16 [4096][800]
//   we    @1638400   bf16 [2304][800]
//   wpb   @2560000   bf16 [768][768]
//   qkvb  @2854912   bf16 [3][12][4096][64]
//   vtb   @7573504   bf16 [12][64][4096]  (keys pi-permuted within 16-groups)
//   attnb @9146368   bf16 [4096][768]

// ---------------------------------------------------------------------------
// Kernel A: build extended weights we[2304][800] and wpb[768][768] (bf16)
__global__ __launch_bounds__(64)
void k_prep_w(const float* __restrict__ Wqkv, const float* __restrict__ Bq,
              const float* __restrict__ Bv, const float* __restrict__ Wp,
              short* __restrict__ we, short* __restrict__ wpb) {
  const int j = blockIdx.x;
  const int l = threadIdx.x;
  if (j < 2304) {
#pragma unroll
    for (int k = 0; k < 12; ++k)
      we[(size_t)j * DK + l + 64 * k] = f2b(Wqkv[(size_t)j * DIMD + l + 64 * k]);
    if (l < 32) {
      int c = 768 + l;
      short v = 0;
      if (l < 4) {
        if (j < 768) v = f2b(Bq[j * 4 + l]);
      } else if (l < 8) {
        if (j >= 1536) v = f2b(Bv[(j - 1536) * 4 + (l - 4)]);
      }
      we[(size_t)j * DK + c] = v;
    }
  } else {
    const int jr = j - 2304;
#pragma unroll
    for (int k = 0; k < 12; ++k)
      wpb[(size_t)jr * DIMD + l + 64 * k] =
          f2b(Wp[(size_t)jr * DIMD + l + 64 * k]);
  }
}

// ---------------------------------------------------------------------------
// Kernel B: build xe[4096][800] = [bf16(x) | 0.25*x@Aq^T | 0.25*x@Av^T | 0]
__global__ __launch_bounds__(64)
void k_prep_x(const float* __restrict__ x, const float* __restrict__ Aq,
              const float* __restrict__ Av, short* __restrict__ xe) {
  const int i = blockIdx.x;
  const int l = threadIdx.x;
  float xv[12];
#pragma unroll
  for (int k = 0; k < 12; ++k) xv[k] = x[(size_t)i * DIMD + l + 64 * k];
#pragma unroll
  for (int k = 0; k < 12; ++k)
    xe[(size_t)i * DK + l + 64 * k] = f2b(xv[k]);
  float a8[8];
#pragma unroll
  for (int o = 0; o < 8; ++o) {
    const float* A = (o < 4) ? (Aq + o * DIMD) : (Av + (o - 4) * DIMD);
    float acc = 0.f;
#pragma unroll
    for (int k = 0; k < 12; ++k) acc = fmaf(xv[k], A[l + 64 * k], acc);
#pragma unroll
    for (int off = 32; off; off >>= 1) acc += __shfl_xor(acc, off, 64);
    a8[o] = acc;
  }
  if (l < 32) {
    float v = 0.f;
#pragma unroll
    for (int o = 0; o < 8; ++o)
      if (l == o) v = 0.25f * a8[o];
    xe[(size_t)i * DK + 768 + l] = (l < 8) ? f2b(v) : (short)0;
  }
}

// ---------------------------------------------------------------------------
// Kernel 2: bf16 MFMA qkv GEMM over extended K=800 (LoRA folded in),
// LDS-staged coalesced epilogue, scatter to qkvb[which][head][n][d].
__global__ __launch_bounds__(256)
void k_qkv(const short* __restrict__ xe, const short* __restrict__ we,
           const float* __restrict__ bqkv, short* __restrict__ qkvb) {
  const int j0 = blockIdx.x * 128;
  const int i0 = blockIdx.y * 128;
  __shared__ short As[128 * 32];
  __shared__ short Bs[128 * 32];
  __shared__ short Cs[128 * 130];
  const int t = threadIdx.x, lane = t & 63, w = t >> 6;
  const int l15 = lane & 15, quad = lane >> 4;
  const int wm = w >> 1, wn = w & 1;

  f32x4 acc[4][4];
#pragma unroll
  for (int a = 0; a < 4; ++a)
#pragma unroll
    for (int b = 0; b < 4; ++b) acc[a][b] = (f32x4){0.f, 0.f, 0.f, 0.f};

  for (int kk = 0; kk < DK; kk += 32) {
    __syncthreads();
#pragma unroll
    for (int rep = 0; rep < 2; ++rep) {
      int c = rep * 256 + w * 64 + lane;
      gl_lds16(xe + (size_t)(i0 + (c >> 2)) * DK + kk + (c & 3) * 8,
               &As[(rep * 256 + w * 64) * 8]);
      gl_lds16(we + (size_t)(j0 + (c >> 2)) * DK + kk + (c & 3) * 8,
               &Bs[(rep * 256 + w * 64) * 8]);
    }
    __syncthreads();
    s16x8 af[4], bf[4];
#pragma unroll
    for (int mt = 0; mt < 4; ++mt)
      af[mt] = *(const s16x8*)&As[(wm * 64 + mt * 16 + l15) * 32 + quad * 8];
#pragma unroll
    for (int nt = 0; nt < 4; ++nt)
      bf[nt] = *(const s16x8*)&Bs[(wn * 64 + nt * 16 + l15) * 32 + quad * 8];
#pragma unroll
    for (int mt = 0; mt < 4; ++mt)
#pragma unroll
      for (int nt = 0; nt < 4; ++nt)
        acc[mt][nt] = MFMA16(af[mt], bf[nt], acc[mt][nt]);
  }

  const int which = j0 / DIMD;
  float bj[4];
#pragma unroll
  for (int nt = 0; nt < 4; ++nt) bj[nt] = bqkv[j0 + wn * 64 + nt * 16 + l15];

#pragma unroll
  for (int mt = 0; mt < 4; ++mt)
#pragma unroll
    for (int r = 0; r < 4; ++r) {
      const int row = wm * 64 + mt * 16 + quad * 4 + r;
#pragma unroll
      for (int nt = 0; nt < 4; ++nt) {
        const int col = wn * 64 + nt * 16 + l15;
        Cs[row * 130 + col] = f2b(acc[mt][nt][r] + bj[nt]);
      }
    }
  __syncthreads();
  const int base_head = (j0 - which * DIMD) >> 6;
#pragma unroll
  for (int rp = 0; rp < 8; ++rp) {
    int f = t + 256 * rp;
    int row = f >> 4, ch = f & 15;
    int head = base_head + (ch >> 3);
    int ddb = (ch & 7) * 8;
    s16x8 v = *(const s16x8*)&Cs[row * 130 + ch * 8];
    *(s16x8*)&qkvb[(((size_t)which * NHD + head) * NTOK + i0 + row) * HDD + ddb] = v;
  }
}

// ---------------------------------------------------------------------------
// Kernel 3: transpose V with key permutation: vtb[head][d][16G + s] =
// V[16G + pi(s)][d], pi = block swap {0,2,1,3} of 4-blocks within each 16.
// This makes PV B-fragments in k_attn coincide with each lane's own packed
// exp() results -> no cross-lane exchange in the attention main loop.
__global__ __launch_bounds__(256)
void k_vt(const short* __restrict__ qkvb, short* __restrict__ vtb) {
  const int head = blockIdx.y;
  const int n0 = blockIdx.x * 64;
  const short* vg = qkvb + ((size_t)(2 * NHD + head)) * NTOK * HDD;
  __shared__ short T[64][68];
  const int t = threadIdx.x;
#pragma unroll
  for (int rp = 0; rp < 4; ++rp) {
    int f = t + 256 * rp;
    int n = f >> 4, c4 = (f & 15) * 4;
    *(short4*)&T[n][c4] = *(const short4*)&vg[(size_t)(n0 + n) * HDD + c4];
  }
  __syncthreads();
#pragma unroll
  for (int rp = 0; rp < 4; ++rp) {
    int f = t + 256 * rp;
    int d = f >> 4, n4 = (f & 15) * 4;
    const int pmap[4] = {0, 2, 1, 3};
    int n4s = (n4 & 48) | (pmap[(n4 >> 2) & 3] << 2);
    short4 o;
    o.x = T[n4s + 0][d]; o.y = T[n4s + 1][d];
    o.z = T[n4s + 2][d]; o.w = T[n4s + 3][d];
    *(short4*)&vtb[((size_t)head * HDD + d) * NTOK + n0 + n4] = o;
  }
}

// ---------------------------------------------------------------------------
// Kernel 4: 32x32x16-MFMA flash attention, swapped operands (S^T / O^T),
// DMA double-buffered staging (r6 structure), permuted-Vt PV (no shuffles).
// grid (64 qblocks, 12 heads), 4 waves. LDS shorts: K0@0, K1@4096, V0@8192,
// V1@12288, bHb@16384..20480 (log2e prefolded).
__global__ __launch_bounds__(256)
void k_attn6(const short* __restrict__ qkvb, const short* __restrict__ vtb,
             const float* __restrict__ relh, const float* __restrict__ relw,
             short* __restrict__ attnb) {
  const int head = blockIdx.y;
  const int hq = blockIdx.x;
  const int n0 = hq * 64;

  __shared__ short sm[20480];
  short* smb = sm;

  const short* qg  = qkvb + (size_t)(0 * NHD + head) * NTOK * HDD;
  const short* kg  = qkvb + (size_t)(1 * NHD + head) * NTOK * HDD;
  const short* vtg = vtb + (size_t)head * HDD * NTOK;

  const int t = threadIdx.x;
  const int w = t >> 6, lane = t & 63;
  const int l31 = lane & 31, h = lane >> 5;
  const int kh = w >> 1, qh = w & 1;
  const int q = qh * 32 + l31;

  // DMA slot: (row, chunk ^ (row&7))
  const int slot = w * 64 + lane;
  const int krow = slot >> 3;
  const int kcol = ((slot & 7) ^ (krow & 7)) * 8;
  const short* gK0 = kg + (size_t)krow * HDD + kcol;
  const short* gK1 = gK0 + 32 * HDD;
  const short* gV0 = vtg + (size_t)krow * NTOK + kcol;
  const short* gV1 = gV0 + (size_t)32 * NTOK;

  // Q B-fragments (persist)
  s16x8 qb[4];
#pragma unroll
  for (int s = 0; s < 4; ++s)
    qb[s] = *(const s16x8*)&qg[(size_t)(n0 + q) * HDD + s * 16 + 8 * h];

  // ---- prologue: RW -> overlay ----
#pragma unroll
  for (int rp = 0; rp < 4; ++rp) {
    int f = t + 256 * rp;
    int d = f >> 3, c = (f & 7) * 8;
    float4 v0 = make_float4(0, 0, 0, 0), v1 = v0;
    if (d < 127) {
      const float* s_ = relw + (size_t)d * HDD + c;
      v0 = *(const float4*)s_; v1 = *(const float4*)(s_ + 4);
    }
    short4 b0, b1;
    b0.x = f2b(v0.x); b0.y = f2b(v0.y); b0.z = f2b(v0.z); b0.w = f2b(v0.w);
    b1.x = f2b(v1.x); b1.y = f2b(v1.y); b1.z = f2b(v1.z); b1.w = f2b(v1.w);
    *(short4*)&smb[d * 72 + c] = b0;
    *(short4*)&smb[d * 72 + c + 4] = b1;
  }
  __syncthreads();

  // M^T = RW @ Q^T (log2e folded at store)
  f32x16 mc0 = (f32x16)(0.f), mc1 = (f32x16)(0.f);
#pragma unroll
  for (int s = 0; s < 4; ++s) {
    s16x8 a0 = *(const s16x8*)&smb[((kh * 2) * 32 + l31) * 72 + s * 16 + 8 * h];
    s16x8 a1 = *(const s16x8*)&smb[((kh * 2 + 1) * 32 + l31) * 72 + s * 16 + 8 * h];
    mc0 = MFMA32(a0, qb[s], mc0);
    mc1 = MFMA32(a1, qb[s], mc1);
  }
  __syncthreads();
#pragma unroll
  for (int reg = 0; reg < 16; ++reg) {
    int dl = (reg & 3) + 8 * (reg >> 2) + 4 * h;
    smb[(kh * 64 + dl) * 64 + q] = f2b(mc0[reg] * 1.44269504f);
    smb[(kh * 64 + 32 + dl) * 64 + q] = f2b(mc1[reg] * 1.44269504f);
  }
  __syncthreads();

  float bwl2[16];
#pragma unroll
  for (int reg = 0; reg < 16; ++reg) {
    int kl64 = kh * 32 + (reg & 3) + 8 * (reg >> 2) + 4 * h;
    int dneed = q - kl64 + 63;  // [0,126]
    bwl2[reg] = b2f(smb[dneed * 64 + q]);
  }
  __syncthreads();

  // RH -> overlay
#pragma unroll
  for (int rp = 0; rp < 2; ++rp) {
    int f = t + 256 * rp;
    int kt = f >> 3, c = (f & 7) * 8;
    const float* s_ = relh + (size_t)(hq + 63 - kt) * HDD + c;
    float4 v0 = *(const float4*)s_, v1 = *(const float4*)(s_ + 4);
    short4 b0, b1;
    b0.x = f2b(v0.x); b0.y = f2b(v0.y); b0.z = f2b(v0.z); b0.w = f2b(v0.w);
    b1.x = f2b(v1.x); b1.y = f2b(v1.y); b1.z = f2b(v1.z); b1.w = f2b(v1.w);
    *(short4*)&smb[kt * 72 + c] = b0;
    *(short4*)&smb[kt * 72 + c + 4] = b1;
  }
  __syncthreads();

  // bH^T = RH @ Q^T -> bHb @16384 (log2e prefolded)
  f32x16 hc = (f32x16)(0.f);
#pragma unroll
  for (int s = 0; s < 4; ++s) {
    s16x8 a = *(const s16x8*)&smb[(kh * 32 + l31) * 72 + s * 16 + 8 * h];
    hc = MFMA32(a, qb[s], hc);
  }
#pragma unroll
  for (int reg = 0; reg < 16; ++reg) {
    int ktl = kh * 32 + (reg & 3) + 8 * (reg >> 2) + 4 * h;
    smb[16384 + ktl * 64 + q] = f2b(hc[reg] * 1.44269504f);
  }
  __syncthreads();  // RH reads done; bHb published; DMA may write [0,16384)

  // bootstrap: tile 0 -> K0, V0
  gl_lds16(gK0, smb + 0 + w * 512);
  gl_lds16(gK1, smb + 2048 + w * 512);
  gl_lds16(gV0, smb + 8192 + w * 512);
  gl_lds16(gV1, smb + 8192 + 2048 + w * 512);
  gK0 += 4096; gK1 += 4096;
  gV0 += 64; gV1 += 64;

  // read bases
  int baseS[4], baseV[2];
#pragma unroll
  for (int s = 0; s < 4; ++s)
    baseS[s] = (kh * 32 + l31) * 64 + (((2 * s + h) ^ (l31 & 7)) * 8);
#pragma unroll
  for (int s2 = 0; s2 < 2; ++s2)
    baseV[s2] = l31 * 64 + (((kh * 4 + s2 * 2 + h) ^ (l31 & 7)) * 8);

  float ps = 0.f;
  f32x16 oc0 = (f32x16)(0.f), oc1 = (f32x16)(0.f);

#define ATTN_ITER(KT, KSRC, VSRC, KDST, VDST)                                  \
  {                                                                            \
    __syncthreads();                                                           \
    if ((KT) < 63) {                                                           \
      gl_lds16(gK0, smb + (KDST) + w * 512);                                   \
      gl_lds16(gK1, smb + (KDST) + 2048 + w * 512);                            \
      gl_lds16(gV0, smb + (VDST) + w * 512);                                   \
      gl_lds16(gV1, smb + (VDST) + 2048 + w * 512);                            \
      gK0 += 4096; gK1 += 4096; gV0 += 64; gV1 += 64;                          \
    }                                                                          \
    f32x16 sc_ = (f32x16)(0.f);                                                \
    _Pragma("unroll") for (int s = 0; s < 4; ++s) {                            \
      s16x8 a = *(const s16x8*)&smb[(KSRC) + baseS[s]];                        \
      sc_ = MFMA32(a, qb[s], sc_);                                             \
    }                                                                          \
    float bhl2 = b2f(smb[16384 + (KT) * 64 + q]);                              \
    float sv[16];                                                              \
    _Pragma("unroll") for (int reg = 0; reg < 16; ++reg) {                     \
      sv[reg] = exp2f(fmaf(0.18033688f, sc_[reg], bhl2 + bwl2[reg]));          \
      ps += sv[reg];                                                           \
    }                                                                          \
    unsigned pk[8];                                                            \
    _Pragma("unroll") for (int i = 0; i < 8; ++i) {                            \
      int rl = 2 * i;                                                          \
      pk[i] = __builtin_amdgcn_perm(__float_as_uint(sv[rl + 1]),               \
                                    __float_as_uint(sv[rl]), 0x07060302u);     \
    }                                                                          \
    _Pragma("unroll") for (int s2 = 0; s2 < 2; ++s2) {                         \
      union { unsigned u[4]; s16x8 v; } B;                                     \
      B.u[0] = pk[4 * s2 + 0];                                                 \
      B.u[1] = pk[4 * s2 + 1];                                                 \
      B.u[2] = pk[4 * s2 + 2];                                                 \
      B.u[3] = pk[4 * s2 + 3];                                                 \
      s16x8 a0 = *(const s16x8*)&smb[(VSRC) + baseV[s2]];                      \
      s16x8 a1 = *(const s16x8*)&smb[(VSRC) + 2048 + baseV[s2]];               \
      oc0 = MFMA32(a0, B.v, oc0);                                              \
      oc1 = MFMA32(a1, B.v, oc1);                                              \
    }                                                                          \
  }

  for (int k2 = 0; k2 < 32; ++k2) {
    ATTN_ITER(2 * k2,     0,    8192,  4096, 12288);
    ATTN_ITER(2 * k2 + 1, 4096, 12288, 0,    8192);
  }
#undef ATTN_ITER

  // ---- epilogue: combine kh halves, normalize, transpose, store ----
  __syncthreads();
  float* obuf = (float*)smb;          // [64][66] floats @0
  float* psb  = (float*)smb + 4224;
  short* tbuf = smb + 8576;           // [64][66] shorts
  ps += __shfl_xor(ps, 32, 64);
  if (kh == 1) {
#pragma unroll
    for (int reg = 0; reg < 16; ++reg) {
      int dl = (reg & 3) + 8 * (reg >> 2) + 4 * h;
      obuf[dl * 66 + q] = oc0[reg];
      obuf[(32 + dl) * 66 + q] = oc1[reg];
    }
    if (lane < 32) psb[q] = ps;
  }
  __syncthreads();
  if (kh == 0) {
    float inv = 1.f / (ps + psb[q]);
#pragma unroll
    for (int reg = 0; reg < 16; ++reg) {
      int dl = (reg & 3) + 8 * (reg >> 2) + 4 * h;
      tbuf[dl * 66 + q] = f2b((oc0[reg] + obuf[dl * 66 + q]) * inv);
      tbuf[(32 + dl) * 66 + q] = f2b((oc1[reg] + obuf[(32 + dl) * 66 + q]) * inv);
    }
  }
  __syncthreads();
  {
    int qq = t >> 2, seg = t & 3;
    unsigned wds[8];
#pragma unroll
    for (int m = 0; m < 8; ++m) {
      unsigned lo = (unsigned short)tbuf[(seg * 16 + 2 * m) * 66 + qq];
      unsigned hi = (unsigned short)tbuf[(seg * 16 + 2 * m + 1) * 66 + qq];
      wds[m] = lo | (hi << 16);
    }
    short* dst = attnb + (size_t)(n0 + qq) * DIMD + head * 64 + seg * 16;
    *(int4*)dst = *(int4*)&wds[0];
    *(int4*)(dst + 8) = *(int4*)&wds[4];
  }
}

// ---------------------------------------------------------------------------
// Kernel 5: bf16 MFMA proj: out = attn @ Wp^T + bp (fp32 out)
__global__ __launch_bounds__(256)
void k_proj(const short* __restrict__ ab, const short* __restrict__ wpb,
            const float* __restrict__ bp, float* __restrict__ out) {
  const int j0 = blockIdx.x * 64;
  const int i0 = blockIdx.y * 128;
  __shared__ short As[128 * 32];
  __shared__ short Bs[64 * 32];
  const int t = threadIdx.x, lane = t & 63, w = t >> 6;
  const int l15 = lane & 15, quad = lane >> 4;
  const int wm = w >> 1, wn = w & 1;

  f32x4 acc[4][2];
#pragma unroll
  for (int a = 0; a < 4; ++a)
#pragma unroll
    for (int b = 0; b < 2; ++b) acc[a][b] = (f32x4){0.f, 0.f, 0.f, 0.f};

  for (int kk = 0; kk < DIMD; kk += 32) {
    __syncthreads();
#pragma unroll
    for (int rep = 0; rep < 2; ++rep) {
      int c = rep * 256 + w * 64 + lane;
      gl_lds16(ab + (size_t)(i0 + (c >> 2)) * DIMD + kk + (c & 3) * 8,
               &As[(rep * 256 + w * 64) * 8]);
    }
    {
      gl_lds16(wpb + (size_t)(j0 + ((w * 64 + lane) >> 2)) * DIMD + kk +
                   ((w * 64 + lane) & 3) * 8,
               &Bs[(w * 64) * 8]);
    }
    __syncthreads();
    s16x8 af[4], bf[2];
#pragma unroll
    for (int mt = 0; mt < 4; ++mt)
      af[mt] = *(const s16x8*)&As[(wm * 64 + mt * 16 + l15) * 32 + quad * 8];
#pragma unroll
    for (int nt = 0; nt < 2; ++nt)
      bf[nt] = *(const s16x8*)&Bs[(wn * 32 + nt * 16 + l15) * 32 + quad * 8];
#pragma unroll
    for (int mt = 0; mt < 4; ++mt)
#pragma unroll
      for (int nt = 0; nt < 2; ++nt)
        acc[mt][nt] = MFMA16(af[mt], bf[nt], acc[mt][nt]);
  }

#pragma unroll
  for (int mt = 0; mt < 4; ++mt)
#pragma unroll
    for (int r = 0; r < 4; ++r) {
      const int i = i0 + wm * 64 + mt * 16 + quad * 4 + r;
#pragma unroll
      for (int nt = 0; nt < 2; ++nt) {
        const int j = j0 + wn * 32 + nt * 16 + l15;
        out[(size_t)i * DIMD + j] = acc[mt][nt][r] + bp[j];
      }
    }
}

// ---------------------------------------------------------------------------
extern "C" void kernel_launch(void* const* d_in, const int* in_sizes, int n_in,
                              void* d_out, int out_size, void* d_ws, size_t ws_size,
                              hipStream_t stream) {
  (void)in_sizes; (void)n_in; (void)out_size; (void)ws_size;
  const float* x    = (const float*)d_in[0];
  const float* Wqkv = (const float*)d_in[1];
  const float* bqkv = (const float*)d_in[2];
  const float* Aq   = (const float*)d_in[3];
  const float* Bq   = (const float*)d_in[4];
  const float* Av   = (const float*)d_in[5];
  const float* Bv   = (const float*)d_in[6];
  const float* relh = (const float*)d_in[7];
  const float* relw = (const float*)d_in[8];
  const float* Wp   = (const float*)d_in[9];
  const float* bp   = (const float*)d_in[10];
  float* out = (float*)d_out;

  float* ws = (float*)d_ws;
  short* xe    = (short*)(ws);
  short* we    = (short*)(ws + 1638400);
  short* wpb   = (short*)(ws + 2560000);
  short* qkvb  = (short*)(ws + 2854912);
  short* vtb   = (short*)(ws + 7573504);
  short* attnb = (short*)(ws + 9146368);

  k_prep_w<<<dim3(3072), dim3(64), 0, stream>>>(Wqkv, Bq, Bv, Wp, we, wpb);
  k_prep_x<<<dim3(NTOK), dim3(64), 0, stream>>>(x, Aq, Av, xe);
  k_qkv<<<dim3(18, 32), dim3(256), 0, stream>>>(xe, we, bqkv, qkvb);
  k_vt<<<dim3(64, NHD), dim3(256), 0, stream>>>(qkvb, vtb);
  k_attn6<<<dim3(64, NHD), dim3(256), 0, stream>>>(qkvb, vtb, relh, relw, attnb);
  k_proj<<<dim3(12, 32), dim3(256), 0, stream>>>(attnb, wpb, bp, out);
}

// Round 9
// 220.408 us; speedup vs baseline: 1.2539x; 1.1018x over previous
//
#include <hip/hip_runtime.h>

// x:(1,64,64,768) -> n=4096 tokens, DIM=768, 12 heads x 64 dim
#define NTOK 4096
#define DIMD 768
#define NHD  12
#define HDD  64
#define DK   800   // extended K: 768 x | 4 lora-q | 4 lora-v | 24 zero

typedef float  f32x2  __attribute__((ext_vector_type(2)));
typedef float  f32x4  __attribute__((ext_vector_type(4)));
typedef float  f32x16 __attribute__((ext_vector_type(16)));
typedef short  s16x8  __attribute__((ext_vector_type(8)));

#define MFMA16(a, b, c) __builtin_amdgcn_mfma_f32_16x16x32_bf16(a, b, c, 0, 0, 0)
#define MFMA32(a, b, c) __builtin_amdgcn_mfma_f32_32x32x16_bf16(a, b, c, 0, 0, 0)

#if __has_builtin(__builtin_amdgcn_exp2f)
#define EXP2(x) __builtin_amdgcn_exp2f(x)
#else
#define EXP2(x) exp2f(x)
#endif

__device__ inline short f2b(float f) {  // fp32 -> bf16 RNE
  unsigned u = __float_as_uint(f);
  u += 0x7FFFu + ((u >> 16) & 1u);
  return (short)(u >> 16);
}
__device__ inline float b2f(short s) {
  return __uint_as_float(((unsigned)(unsigned short)s) << 16);
}
__device__ inline void gl_lds16(const short* g, short* l) {
  __builtin_amdgcn_global_load_lds(
      (const __attribute__((address_space(1))) unsigned int*)g,
      (__attribute__((address_space(3))) unsigned int*)l, 16, 0, 0);
}

// ws layout (float units):
//   xe    @0         bf16 [4096][800]
//   we    @1638400   bf16 [2304][800]
//   wpb   @2560000   bf16 [768][768]
//   qkvb  @2854912   bf16 [3][12][4096][64]  (V third unused)
//   vtb   @7573504   bf16 [12][64][4096]  (keys pi-permuted within 16-groups)
//   attnb @9146368   bf16 [4096][768]

// ---------------------------------------------------------------------------
// Kernel A: build extended weights we[2304][800] and wpb[768][768] (bf16)
__global__ __launch_bounds__(64)
void k_prep_w(const float* __restrict__ Wqkv, const float* __restrict__ Bq,
              const float* __restrict__ Bv, const float* __restrict__ Wp,
              short* __restrict__ we, short* __restrict__ wpb) {
  const int j = blockIdx.x;
  const int l = threadIdx.x;
  if (j < 2304) {
#pragma unroll
    for (int k = 0; k < 12; ++k)
      we[(size_t)j * DK + l + 64 * k] = f2b(Wqkv[(size_t)j * DIMD + l + 64 * k]);
    if (l < 32) {
      int c = 768 + l;
      short v = 0;
      if (l < 4) {
        if (j < 768) v = f2b(Bq[j * 4 + l]);
      } else if (l < 8) {
        if (j >= 1536) v = f2b(Bv[(j - 1536) * 4 + (l - 4)]);
      }
      we[(size_t)j * DK + c] = v;
    }
  } else {
    const int jr = j - 2304;
#pragma unroll
    for (int k = 0; k < 12; ++k)
      wpb[(size_t)jr * DIMD + l + 64 * k] =
          f2b(Wp[(size_t)jr * DIMD + l + 64 * k]);
  }
}

// ---------------------------------------------------------------------------
// Kernel B: build xe[4096][800] = [bf16(x) | 0.25*x@Aq^T | 0.25*x@Av^T | 0]
__global__ __launch_bounds__(64)
void k_prep_x(const float* __restrict__ x, const float* __restrict__ Aq,
              const float* __restrict__ Av, short* __restrict__ xe) {
  const int i = blockIdx.x;
  const int l = threadIdx.x;
  float xv[12];
#pragma unroll
  for (int k = 0; k < 12; ++k) xv[k] = x[(size_t)i * DIMD + l + 64 * k];
#pragma unroll
  for (int k = 0; k < 12; ++k)
    xe[(size_t)i * DK + l + 64 * k] = f2b(xv[k]);
  float a8[8];
#pragma unroll
  for (int o = 0; o < 8; ++o) {
    const float* A = (o < 4) ? (Aq + o * DIMD) : (Av + (o - 4) * DIMD);
    float acc = 0.f;
#pragma unroll
    for (int k = 0; k < 12; ++k) acc = fmaf(xv[k], A[l + 64 * k], acc);
#pragma unroll
    for (int off = 32; off; off >>= 1) acc += __shfl_xor(acc, off, 64);
    a8[o] = acc;
  }
  if (l < 32) {
    float v = 0.f;
#pragma unroll
    for (int o = 0; o < 8; ++o)
      if (l == o) v = 0.25f * a8[o];
    xe[(size_t)i * DK + 768 + l] = (l < 8) ? f2b(v) : (short)0;
  }
}

// ---------------------------------------------------------------------------
// Kernel 2: bf16 MFMA qkv GEMM over extended K=800 (LoRA folded in).
// q/k thirds -> qkvb[which][head][n][d] (coalesced via Cs).
// v third    -> vtb[head][d][n] directly (transposed + pi-permuted via Cs).
__global__ __launch_bounds__(256)
void k_qkv(const short* __restrict__ xe, const short* __restrict__ we,
           const float* __restrict__ bqkv, short* __restrict__ qkvb,
           short* __restrict__ vtb) {
  const int j0 = blockIdx.x * 128;
  const int i0 = blockIdx.y * 128;
  __shared__ short As[128 * 32];
  __shared__ short Bs[128 * 32];
  __shared__ short Cs[128 * 130];
  const int t = threadIdx.x, lane = t & 63, w = t >> 6;
  const int l15 = lane & 15, quad = lane >> 4;
  const int wm = w >> 1, wn = w & 1;

  f32x4 acc[4][4];
#pragma unroll
  for (int a = 0; a < 4; ++a)
#pragma unroll
    for (int b = 0; b < 4; ++b) acc[a][b] = (f32x4){0.f, 0.f, 0.f, 0.f};

  for (int kk = 0; kk < DK; kk += 32) {
    __syncthreads();
#pragma unroll
    for (int rep = 0; rep < 2; ++rep) {
      int c = rep * 256 + w * 64 + lane;
      gl_lds16(xe + (size_t)(i0 + (c >> 2)) * DK + kk + (c & 3) * 8,
               &As[(rep * 256 + w * 64) * 8]);
      gl_lds16(we + (size_t)(j0 + (c >> 2)) * DK + kk + (c & 3) * 8,
               &Bs[(rep * 256 + w * 64) * 8]);
    }
    __syncthreads();
    s16x8 af[4], bf[4];
#pragma unroll
    for (int mt = 0; mt < 4; ++mt)
      af[mt] = *(const s16x8*)&As[(wm * 64 + mt * 16 + l15) * 32 + quad * 8];
#pragma unroll
    for (int nt = 0; nt < 4; ++nt)
      bf[nt] = *(const s16x8*)&Bs[(wn * 64 + nt * 16 + l15) * 32 + quad * 8];
#pragma unroll
    for (int mt = 0; mt < 4; ++mt)
#pragma unroll
      for (int nt = 0; nt < 4; ++nt)
        acc[mt][nt] = MFMA16(af[mt], bf[nt], acc[mt][nt]);
  }

  const int which = j0 / DIMD;
  float bj[4];
#pragma unroll
  for (int nt = 0; nt < 4; ++nt) bj[nt] = bqkv[j0 + wn * 64 + nt * 16 + l15];

#pragma unroll
  for (int mt = 0; mt < 4; ++mt)
#pragma unroll
    for (int r = 0; r < 4; ++r) {
      const int row = wm * 64 + mt * 16 + quad * 4 + r;
#pragma unroll
      for (int nt = 0; nt < 4; ++nt) {
        const int col = wn * 64 + nt * 16 + l15;
        Cs[row * 130 + col] = f2b(acc[mt][nt][r] + bj[nt]);
      }
    }
  __syncthreads();
  const int base_head = (j0 - which * DIMD) >> 6;
  if (which != 2) {
    // q/k: coalesced row stores into qkvb[which][head][n][d]
#pragma unroll
    for (int rp = 0; rp < 8; ++rp) {
      int f = t + 256 * rp;
      int row = f >> 4, ch = f & 15;
      int head = base_head + (ch >> 3);
      int ddb = (ch & 7) * 8;
      s16x8 v = *(const s16x8*)&Cs[row * 130 + ch * 8];
      *(s16x8*)&qkvb[(((size_t)which * NHD + head) * NTOK + i0 + row) * HDD + ddb] = v;
    }
  } else {
    // v: transposed + pi-permuted store into vtb[head][d][n]
    // pi(s) = (s&0x70) | pmap[(s>>2)&3]<<2 | (s&3), pmap = {0,2,1,3}
#pragma unroll
    for (int rp = 0; rp < 8; ++rp) {
      int f = t + 256 * rp;             // 0..2047 = (dcol 0..127, nch 0..15)
      int dcol = f >> 4, n8 = (f & 15) * 8;
      unsigned wds[4];
#pragma unroll
      for (int m = 0; m < 4; ++m) {
        int s0 = n8 + 2 * m, s1 = s0 + 1;
        int sr0 = (s0 & 0x70) | ((((s0 >> 2) & 3) == 1 ? 2 : ((s0 >> 2) & 3) == 2 ? 1 : ((s0 >> 2) & 3)) << 2) | (s0 & 3);
        int sr1 = (s1 & 0x70) | ((((s1 >> 2) & 3) == 1 ? 2 : ((s1 >> 2) & 3) == 2 ? 1 : ((s1 >> 2) & 3)) << 2) | (s1 & 3);
        unsigned lo = (unsigned short)Cs[sr0 * 130 + dcol];
        unsigned hi = (unsigned short)Cs[sr1 * 130 + dcol];
        wds[m] = lo | (hi << 16);
      }
      short* dst = vtb + ((size_t)(base_head * 64) + dcol) * NTOK + i0 + n8;
      *(int4*)dst = *(int4*)&wds[0];
    }
  }
}

// ---------------------------------------------------------------------------
// Kernel 4: 32x32x16-MFMA flash attention, swapped operands (S^T / O^T),
// DMA double-buffered staging, permuted-Vt PV (no cross-lane exchange),
// packed-f32 softmax + raw v_exp_f32. grid (64 qblocks, 12 heads), 4 waves.
// LDS shorts: K0@0, K1@4096, V0@8192, V1@12288, bHb@16384..20480 (log2e folded).
__global__ __launch_bounds__(256)
void k_attn7(const short* __restrict__ qkvb, const short* __restrict__ vtb,
             const float* __restrict__ relh, const float* __restrict__ relw,
             short* __restrict__ attnb) {
  const int head = blockIdx.y;
  const int hq = blockIdx.x;
  const int n0 = hq * 64;

  __shared__ short sm[20480];
  short* smb = sm;

  const short* qg  = qkvb + (size_t)(0 * NHD + head) * NTOK * HDD;
  const short* kg  = qkvb + (size_t)(1 * NHD + head) * NTOK * HDD;
  const short* vtg = vtb + (size_t)head * HDD * NTOK;

  const int t = threadIdx.x;
  const int w = t >> 6, lane = t & 63;
  const int l31 = lane & 31, h = lane >> 5;
  const int kh = w >> 1, qh = w & 1;
  const int q = qh * 32 + l31;

  // DMA slot: (row, chunk ^ (row&7))
  const int slot = w * 64 + lane;
  const int krow = slot >> 3;
  const int kcol = ((slot & 7) ^ (krow & 7)) * 8;
  const short* gK0 = kg + (size_t)krow * HDD + kcol;
  const short* gK1 = gK0 + 32 * HDD;
  const short* gV0 = vtg + (size_t)krow * NTOK + kcol;
  const short* gV1 = gV0 + (size_t)32 * NTOK;

  // Q B-fragments (persist)
  s16x8 qb[4];
#pragma unroll
  for (int s = 0; s < 4; ++s)
    qb[s] = *(const s16x8*)&qg[(size_t)(n0 + q) * HDD + s * 16 + 8 * h];

  // ---- prologue: RW -> overlay ----
#pragma unroll
  for (int rp = 0; rp < 4; ++rp) {
    int f = t + 256 * rp;
    int d = f >> 3, c = (f & 7) * 8;
    float4 v0 = make_float4(0, 0, 0, 0), v1 = v0;
    if (d < 127) {
      const float* s_ = relw + (size_t)d * HDD + c;
      v0 = *(const float4*)s_; v1 = *(const float4*)(s_ + 4);
    }
    short4 b0, b1;
    b0.x = f2b(v0.x); b0.y = f2b(v0.y); b0.z = f2b(v0.z); b0.w = f2b(v0.w);
    b1.x = f2b(v1.x); b1.y = f2b(v1.y); b1.z = f2b(v1.z); b1.w = f2b(v1.w);
    *(short4*)&smb[d * 72 + c] = b0;
    *(short4*)&smb[d * 72 + c + 4] = b1;
  }
  __syncthreads();

  // M^T = RW @ Q^T (log2e folded at store)
  f32x16 mc0 = (f32x16)(0.f), mc1 = (f32x16)(0.f);
#pragma unroll
  for (int s = 0; s < 4; ++s) {
    s16x8 a0 = *(const s16x8*)&smb[((kh * 2) * 32 + l31) * 72 + s * 16 + 8 * h];
    s16x8 a1 = *(const s16x8*)&smb[((kh * 2 + 1) * 32 + l31) * 72 + s * 16 + 8 * h];
    mc0 = MFMA32(a0, qb[s], mc0);
    mc1 = MFMA32(a1, qb[s], mc1);
  }
  __syncthreads();
#pragma unroll
  for (int reg = 0; reg < 16; ++reg) {
    int dl = (reg & 3) + 8 * (reg >> 2) + 4 * h;
    smb[(kh * 64 + dl) * 64 + q] = f2b(mc0[reg] * 1.44269504f);
    smb[(kh * 64 + 32 + dl) * 64 + q] = f2b(mc1[reg] * 1.44269504f);
  }
  __syncthreads();

  f32x2 bw2[8];
#pragma unroll
  for (int i = 0; i < 8; ++i)
#pragma unroll
    for (int p = 0; p < 2; ++p) {
      int reg = 2 * i + p;
      int kl64 = kh * 32 + (reg & 3) + 8 * (reg >> 2) + 4 * h;
      int dneed = q - kl64 + 63;  // [0,126]
      bw2[i][p] = b2f(smb[dneed * 64 + q]);
    }
  __syncthreads();

  // RH -> overlay
#pragma unroll
  for (int rp = 0; rp < 2; ++rp) {
    int f = t + 256 * rp;
    int kt = f >> 3, c = (f & 7) * 8;
    const float* s_ = relh + (size_t)(hq + 63 - kt) * HDD + c;
    float4 v0 = *(const float4*)s_, v1 = *(const float4*)(s_ + 4);
    short4 b0, b1;
    b0.x = f2b(v0.x); b0.y = f2b(v0.y); b0.z = f2b(v0.z); b0.w = f2b(v0.w);
    b1.x = f2b(v1.x); b1.y = f2b(v1.y); b1.z = f2b(v1.z); b1.w = f2b(v1.w);
    *(short4*)&smb[kt * 72 + c] = b0;
    *(short4*)&smb[kt * 72 + c + 4] = b1;
  }
  __syncthreads();

  // bH^T = RH @ Q^T -> bHb @16384 (log2e prefolded)
  f32x16 hc = (f32x16)(0.f);
#pragma unroll
  for (int s = 0; s < 4; ++s) {
    s16x8 a = *(const s16x8*)&smb[(kh * 32 + l31) * 72 + s * 16 + 8 * h];
    hc = MFMA32(a, qb[s], hc);
  }
#pragma unroll
  for (int reg = 0; reg < 16; ++reg) {
    int ktl = kh * 32 + (reg & 3) + 8 * (reg >> 2) + 4 * h;
    smb[16384 + ktl * 64 + q] = f2b(hc[reg] * 1.44269504f);
  }
  __syncthreads();  // RH reads done; bHb published; DMA may write [0,16384)

  // bootstrap: tile 0 -> K0, V0
  gl_lds16(gK0, smb + 0 + w * 512);
  gl_lds16(gK1, smb + 2048 + w * 512);
  gl_lds16(gV0, smb + 8192 + w * 512);
  gl_lds16(gV1, smb + 8192 + 2048 + w * 512);
  gK0 += 4096; gK1 += 4096;
  gV0 += 64; gV1 += 64;

  // read bases
  int baseS[4], baseV[2];
#pragma unroll
  for (int s = 0; s < 4; ++s)
    baseS[s] = (kh * 32 + l31) * 64 + (((2 * s + h) ^ (l31 & 7)) * 8);
#pragma unroll
  for (int s2 = 0; s2 < 2; ++s2)
    baseV[s2] = l31 * 64 + (((kh * 4 + s2 * 2 + h) ^ (l31 & 7)) * 8);

  f32x2 ps2 = (f32x2)(0.f);
  f32x16 oc0 = (f32x16)(0.f), oc1 = (f32x16)(0.f);

#define ATTN_ITER(KT, KSRC, VSRC, KDST, VDST)                                  \
  {                                                                            \
    __syncthreads();                                                           \
    if ((KT) < 63) {                                                           \
      gl_lds16(gK0, smb + (KDST) + w * 512);                                   \
      gl_lds16(gK1, smb + (KDST) + 2048 + w * 512);                            \
      gl_lds16(gV0, smb + (VDST) + w * 512);                                   \
      gl_lds16(gV1, smb + (VDST) + 2048 + w * 512);                            \
      gK0 += 4096; gK1 += 4096; gV0 += 64; gV1 += 64;                          \
    }                                                                          \
    f32x16 sc_ = (f32x16)(0.f);                                                \
    _Pragma("unroll") for (int s = 0; s < 4; ++s) {                            \
      s16x8 a = *(const s16x8*)&smb[(KSRC) + baseS[s]];                        \
      sc_ = MFMA32(a, qb[s], sc_);                                             \
    }                                                                          \
    float bhl2 = b2f(smb[16384 + (KT) * 64 + q]);                              \
    unsigned pk[8];                                                            \
    _Pragma("unroll") for (int i = 0; i < 8; ++i) {                            \
      f32x2 s2;                                                                \
      s2[0] = sc_[2 * i]; s2[1] = sc_[2 * i + 1];                              \
      f32x2 r = s2 * 0.18033688f + (bw2[i] + bhl2);                            \
      float e0 = EXP2(r[0]);                                                   \
      float e1 = EXP2(r[1]);                                                   \
      f32x2 e2; e2[0] = e0; e2[1] = e1;                                        \
      ps2 += e2;                                                               \
      pk[i] = __builtin_amdgcn_perm(__float_as_uint(e1),                       \
                                    __float_as_uint(e0), 0x07060302u);         \
    }                                                                          \
    _Pragma("unroll") for (int s2i = 0; s2i < 2; ++s2i) {                      \
      union { unsigned u[4]; s16x8 v; } B;                                     \
      B.u[0] = pk[4 * s2i + 0];                                                \
      B.u[1] = pk[4 * s2i + 1];                                                \
      B.u[2] = pk[4 * s2i + 2];                                                \
      B.u[3] = pk[4 * s2i + 3];                                                \
      s16x8 a0 = *(const s16x8*)&smb[(VSRC) + baseV[s2i]];                     \
      s16x8 a1 = *(const s16x8*)&smb[(VSRC) + 2048 + baseV[s2i]];              \
      oc0 = MFMA32(a0, B.v, oc0);                                              \
      oc1 = MFMA32(a1, B.v, oc1);                                              \
    }                                                                          \
  }

  for (int k2 = 0; k2 < 32; ++k2) {
    ATTN_ITER(2 * k2,     0,    8192,  4096, 12288);
    ATTN_ITER(2 * k2 + 1, 4096, 12288, 0,    8192);
  }
#undef ATTN_ITER

  // ---- epilogue: combine kh halves, normalize, transpose, store ----
  __syncthreads();
  float ps = ps2[0] + ps2[1];
  float* obuf = (float*)smb;          // [64][66] floats @0
  float* psb  = (float*)smb + 4224;
  short* tbuf = smb + 8576;           // [64][66] shorts
  ps += __shfl_xor(ps, 32, 64);
  if (kh == 1) {
#pragma unroll
    for (int reg = 0; reg < 16; ++reg) {
      int dl = (reg & 3) + 8 * (reg >> 2) + 4 * h;
      obuf[dl * 66 + q] = oc0[reg];
      obuf[(32 + dl) * 66 + q] = oc1[reg];
    }
    if (lane < 32) psb[q] = ps;
  }
  __syncthreads();
  if (kh == 0) {
    float inv = 1.f / (ps + psb[q]);
#pragma unroll
    for (int reg = 0; reg < 16; ++reg) {
      int dl = (reg & 3) + 8 * (reg >> 2) + 4 * h;
      tbuf[dl * 66 + q] = f2b((oc0[reg] + obuf[dl * 66 + q]) * inv);
      tbuf[(32 + dl) * 66 + q] = f2b((oc1[reg] + obuf[(32 + dl) * 66 + q]) * inv);
    }
  }
  __syncthreads();
  {
    int qq = t >> 2, seg = t & 3;
    unsigned wds[8];
#pragma unroll
    for (int m = 0; m < 8; ++m) {
      unsigned lo = (unsigned short)tbuf[(seg * 16 + 2 * m) * 66 + qq];
      unsigned hi = (unsigned short)tbuf[(seg * 16 + 2 * m + 1) * 66 + qq];
      wds[m] = lo | (hi << 16);
    }
    short* dst = attnb + (size_t)(n0 + qq) * DIMD + head * 64 + seg * 16;
    *(int4*)dst = *(int4*)&wds[0];
    *(int4*)(dst + 8) = *(int4*)&wds[4];
  }
}

// ---------------------------------------------------------------------------
// Kernel 5: bf16 MFMA proj: out = attn @ Wp^T + bp (fp32 out)
__global__ __launch_bounds__(256)
void k_proj(const short* __restrict__ ab, const short* __restrict__ wpb,
            const float* __restrict__ bp, float* __restrict__ out) {
  const int j0 = blockIdx.x * 64;
  const int i0 = blockIdx.y * 128;
  __shared__ short As[128 * 32];
  __shared__ short Bs[64 * 32];
  const int t = threadIdx.x, lane = t & 63, w = t >> 6;
  const int l15 = lane & 15, quad = lane >> 4;
  const int wm = w >> 1, wn = w & 1;

  f32x4 acc[4][2];
#pragma unroll
  for (int a = 0; a < 4; ++a)
#pragma unroll
    for (int b = 0; b < 2; ++b) acc[a][b] = (f32x4){0.f, 0.f, 0.f, 0.f};

  for (int kk = 0; kk < DIMD; kk += 32) {
    __syncthreads();
#pragma unroll
    for (int rep = 0; rep < 2; ++rep) {
      int c = rep * 256 + w * 64 + lane;
      gl_lds16(ab + (size_t)(i0 + (c >> 2)) * DIMD + kk + (c & 3) * 8,
               &As[(rep * 256 + w * 64) * 8]);
    }
    {
      gl_lds16(wpb + (size_t)(j0 + ((w * 64 + lane) >> 2)) * DIMD + kk +
                   ((w * 64 + lane) & 3) * 8,
               &Bs[(w * 64) * 8]);
    }
    __syncthreads();
    s16x8 af[4], bf[2];
#pragma unroll
    for (int mt = 0; mt < 4; ++mt)
      af[mt] = *(const s16x8*)&As[(wm * 64 + mt * 16 + l15) * 32 + quad * 8];
#pragma unroll
    for (int nt = 0; nt < 2; ++nt)
      bf[nt] = *(const s16x8*)&Bs[(wn * 32 + nt * 16 + l15) * 32 + quad * 8];
#pragma unroll
    for (int mt = 0; mt < 4; ++mt)
#pragma unroll
      for (int nt = 0; nt < 2; ++nt)
        acc[mt][nt] = MFMA16(af[mt], bf[nt], acc[mt][nt]);
  }

#pragma unroll
  for (int mt = 0; mt < 4; ++mt)
#pragma unroll
    for (int r = 0; r < 4; ++r) {
      const int i = i0 + wm * 64 + mt * 16 + quad * 4 + r;
#pragma unroll
      for (int nt = 0; nt < 2; ++nt) {
        const int j = j0 + wn * 32 + nt * 16 + l15;
        out[(size_t)i * DIMD + j] = acc[mt][nt][r] + bp[j];
      }
    }
}

// ---------------------------------------------------------------------------
extern "C" void kernel_launch(void* const* d_in, const int* in_sizes, int n_in,
                              void* d_out, int out_size, void* d_ws, size_t ws_size,
                              hipStream_t stream) {
  (void)in_sizes; (void)n_in; (void)out_size; (void)ws_size;
  const float* x    = (const float*)d_in[0];
  const float* Wqkv = (const float*)d_in[1];
  const float* bqkv = (const float*)d_in[2];
  const float* Aq   = (const float*)d_in[3];
  const float* Bq   = (const float*)d_in[4];
  const float* Av   = (const float*)d_in[5];
  const float* Bv   = (const float*)d_in[6];
  const float* relh = (const float*)d_in[7];
  const float* relw = (const float*)d_in[8];
  const float* Wp   = (const float*)d_in[9];
  const float* bp   = (const float*)d_in[10];
  float* out = (float*)d_out;

  float* ws = (float*)d_ws;
  short* xe    = (short*)(ws);
  short* we    = (short*)(ws + 1638400);
  short* wpb   = (short*)(ws + 2560000);
  short* qkvb  = (short*)(ws + 2854912);
  short* vtb   = (short*)(ws + 7573504);
  short* attnb = (short*)(ws + 9146368);

  k_prep_w<<<dim3(3072), dim3(64), 0, stream>>>(Wqkv, Bq, Bv, Wp, we, wpb);
  k_prep_x<<<dim3(NTOK), dim3(64), 0, stream>>>(x, Aq, Av, xe);
  k_qkv<<<dim3(18, 32), dim3(256), 0, stream>>>(xe, we, bqkv, qkvb, vtb);
  k_attn7<<<dim3(64, NHD), dim3(256), 0, stream>>>(qkvb, vtb, relh, relw, attnb);
  k_proj<<<dim3(12, 32), dim3(256), 0, stream>>>(attnb, wpb, bp, out);
}